// Round 5
// baseline (273.114 us; speedup 1.0000x reference)
//
#include <hip/hip_runtime.h>
#include <hip/hip_bf16.h>

// RGCN layer: out = relu(x @ W_self^T + b + agg/deg)
// Pipeline v15 (4 dispatches): aggregate+gemm FUSED (A matrix never touches HBM)
//   1. prep: xb = bf16(x), Bt = bf16([W_rel; W_self^T]), zero bucket cursors
//   2. coarse: edges -> 782 buckets of 64 dst-nodes; 4B packed records
//   3. fine: one block per bucket; LDS hist/scan/scatter -> (dst,rel)-sorted + x8 pad
//   4. fused: 32 nodes/block.
//      phase 1: 4 waves x 8 nodes gather (8-batched scalar stream, flush-on-rel-change)
//               into a 72KB XOR-swizzled LDS A-tile [32][1152] (incl. self xb cols)
//      phase 2: barrier-free GEMM: A-frags from LDS, B-frags straight from global
//               (Bt = 288KB, L2-resident), MFMA 16x16x32, relu+bias epilogue

#define D 128
#define RNUM 8
#define KREL (RNUM * D)      // 1024
#define KTOT (KREL + D)      // 1152
#define BLK_M 32             // nodes per fused block
#define ROWB (KTOT * 2)      // A-tile row pitch in bytes (2304)

#define BSHIFT 6             // 64 nodes per bucket
#define BRANGE 64
#define BCAP   2048          // slots per bucket region (avg fill ~1250)
#define NBKT_MAX 784
#define CSTRIDE 16           // bucket cursor padding (ints) to spread atomic lines

typedef short short8 __attribute__((ext_vector_type(8)));
typedef float float4v __attribute__((ext_vector_type(4)));
typedef float float2v __attribute__((ext_vector_type(2)));

// fp32 -> bf16 round-nearest-even (bit pattern)
static __device__ __forceinline__ unsigned int f2b(float f) {
    unsigned int u = __float_as_uint(f);
    return (u + 0x7fffu + ((u >> 16) & 1u)) >> 16;
}
static __device__ __forceinline__ float b2f_lo(unsigned int u) {
    return __uint_as_float(u << 16);
}
static __device__ __forceinline__ float b2f_hi(unsigned int u) {
    return __uint_as_float(u & 0xffff0000u);
}

// A-tile LDS byte address for a 4B store covering elems [elem2, elem2+1] of row nl.
// 16B pieces XOR-swizzled in their low 3 bits by (nl & 7).
static __device__ __forceinline__ int at4(int nl, int elem2) {
    int byte = elem2 * 2;
    int P = byte >> 4;
    int Ps = (P & ~7) | ((P ^ nl) & 7);
    return nl * ROWB + Ps * 16 + (byte & 15);
}

// ---------- prep (3 block ranges): xb | Bt | zero bucket cursors ----------
__global__ void prep_kernel(const float* __restrict__ x,
                            const float* __restrict__ W_rel,
                            const float* __restrict__ W_self,
                            unsigned short* __restrict__ xb,
                            unsigned short* __restrict__ Bt,
                            int* __restrict__ gcur,
                            int Nn, int xb_blocks, int bt_blocks, int gz) {
    if (blockIdx.x < (unsigned)xb_blocks) {
        int t = blockIdx.x * 256 + threadIdx.x;
        int n = t >> 5;              // 32 threads/row, 4 cols each
        int c = (t & 31) * 4;
        if (n >= Nn) return;
        float4 v = *(const float4*)(x + (size_t)n * D + c);
        unsigned int p0 = f2b(v.x) | (f2b(v.y) << 16);
        unsigned int p1 = f2b(v.z) | (f2b(v.w) << 16);
        *(uint2*)(xb + (size_t)n * D + c) = make_uint2(p0, p1);
    } else if (blockIdx.x < (unsigned)(xb_blocks + bt_blocks)) {
        int idx = (blockIdx.x - xb_blocks) * 256 + threadIdx.x;
        if (idx >= 128 * KTOT) return;
        int o = idx / KTOT;
        int k = idx - o * KTOT;
        float v = (k < KREL) ? W_rel[(size_t)k * D + o]   // [r][d][o] flat = k*128+o
                             : W_self[(size_t)o * D + (k - KREL)];
        Bt[idx] = (unsigned short)f2b(v);
    } else {
        int idx = (blockIdx.x - xb_blocks - bt_blocks) * 256 + threadIdx.x;
        if (idx < gz) gcur[idx] = 0;
    }
}

// ---------- coarse: edges -> buckets, block-aggregated reservation ----------
__global__ __launch_bounds__(256) void coarse_kernel(
        const int* __restrict__ ei, const int* __restrict__ et,
        int* __restrict__ gcur, int* __restrict__ data, int E, int nbkt) {
    __shared__ int cnt[NBKT_MAX];
    int t = threadIdx.x;
    for (int i = t; i < nbkt; i += 256) cnt[i] = 0;
    __syncthreads();

    int rec[8], rb[8], rk[8];
    int e0 = blockIdx.x * 2048;
#pragma unroll
    for (int j = 0; j < 8; ++j) {
        int e = e0 + j * 256 + t;
        bool ok = e < E;
        int s = ok ? ei[e] : 0;
        int d = ok ? ei[E + e] : 0;
        int r = ok ? et[e] : 0;
        int bkt = d >> BSHIFT;
        rec[j] = s | ((d & (BRANGE - 1)) << 16) | (r << 22);
        rb[j] = ok ? bkt : -1;
        rk[j] = ok ? atomicAdd(&cnt[bkt], 1) : 0;
    }
    __syncthreads();

    // reserve global space per nonempty bucket; store absolute write base in cnt[]
    for (int i = t; i < nbkt; i += 256) {
        int c = cnt[i];
        if (c) cnt[i] = i * BCAP + atomicAdd(&gcur[i * CSTRIDE], c);
    }
    __syncthreads();

#pragma unroll
    for (int j = 0; j < 8; ++j) {
        if (rb[j] >= 0) {
            int pos = cnt[rb[j]] + rk[j];
            if (pos < (rb[j] + 1) * BCAP)   // capacity guard (never hit on sane data)
                data[pos] = rec[j];
        }
    }
}

// ---------- fine: one block per bucket; LDS hist + scan + in-place scatter ----------
__global__ __launch_bounds__(256) void fine_kernel(
        int* __restrict__ data, const int* __restrict__ gcur,
        int* __restrict__ offsets, int* __restrict__ deg, int Nn) {
    __shared__ int recs[BCAP];            // 8 KB
    __shared__ int hist[BRANGE * RNUM];   // 2 KB: counts, then converted to cursors
    int b = blockIdx.x;
    int t = threadIdx.x;
    int gbase = b * BCAP;
    int cnt = gcur[b * CSTRIDE];
    if (cnt > BCAP) cnt = BCAP;

    for (int i = t; i < BRANGE * RNUM; i += 256) hist[i] = 0;
    __syncthreads();

    // stage records to LDS + per-(node,rel) histogram (LDS atomics)
    for (int i = t; i < cnt; i += 256) {
        int rec = data[gbase + i];
        recs[i] = rec;
        int n = (rec >> 16) & (BRANGE - 1);
        int r = (rec >> 22) & 7;
        atomicAdd(&hist[n * RNUM + r], 1);
    }
    __syncthreads();

    // first wave: per-node padded scan, emit offsets/deg, sentinels, rel cursors
    if (t < BRANGE) {
        int dsum = 0;
#pragma unroll
        for (int r = 0; r < RNUM; ++r) dsum += hist[t * RNUM + r];
        int pad = (dsum + 7) & ~7;
        int x = pad;                       // inclusive scan across 64 lanes
        for (int off = 1; off < 64; off <<= 1) {
            int y = __shfl_up(x, off);
            if (t >= off) x += y;
        }
        int nb = gbase + (x - pad);        // node base (exclusive prefix)
        int n0 = b * BRANGE + t;
        if (n0 < Nn) { offsets[n0] = nb; deg[n0] = dsum; }
        for (int i = dsum; i < pad; ++i)
            data[nb + i] = (int)0xF0000000u;   // sentinel: rel 15
        int q = nb;
#pragma unroll
        for (int r = 0; r < RNUM; ++r) { int c = hist[t * RNUM + r]; hist[t * RNUM + r] = q; q += c; }
    }
    __syncthreads();

    // scatter in place (reads are fully staged in LDS)
    for (int i = t; i < cnt; i += 256) {
        int rec = recs[i];
        int n = (rec >> 16) & (BRANGE - 1);
        int r = (rec >> 22) & 7;
        int pos = atomicAdd(&hist[n * RNUM + r], 1);
        data[pos] = (rec & 0xFFFF) | (r << 28);
    }
}

// ---------- fused: aggregate into LDS A-tile, then barrier-free GEMM ----------
__global__ __launch_bounds__(256) void fused_kernel(
        const unsigned short* __restrict__ xb,
        const int* __restrict__ offsets,      // node base into sorted, multiple of 8
        const int* __restrict__ deg,          // real in-degree
        const int* __restrict__ sorted,       // src | rel<<28, sentinel 0xF0000000 padded
        const unsigned short* __restrict__ Bt,
        const float* __restrict__ bias,
        float* __restrict__ out,
        int Nn) {
    __shared__ unsigned short At[BLK_M * KTOT];   // 73728 B, piece-swizzled

    const int tid   = threadIdx.x;
    const int lane  = tid & 63;
    const int w     = tid >> 6;
    const int node0 = blockIdx.x * BLK_M;
    const int laneoff = lane * 2;

    // ======== phase 1: gather 8 nodes per wave into At ========
    for (int i = 0; i < 8; ++i) {
        int node = node0 + w * 8 + i;
        if (node >= Nn) break;                 // wave-uniform
        int nl = w * 8 + i;

        int b0 = __builtin_amdgcn_readfirstlane(offsets[node]);
        int dg = __builtin_amdgcn_readfirstlane(deg[node]);
        int b1 = b0 + ((dg + 7) & ~7);
        float inv = 1.0f / fmaxf((float)dg, 1.0f);

        unsigned wmask = 0;
        int cur = 8;                           // 8 = trash (sentinels / start)
        float2v racc = {0.0f, 0.0f};

        for (int e = b0; e < b1; e += 8) {
            int pv[8];
#pragma unroll
            for (int j = 0; j < 8; ++j)
                pv[j] = __builtin_amdgcn_readfirstlane(sorted[e + j]);   // SGPR
            unsigned int u[8];
#pragma unroll
            for (int j = 0; j < 8; ++j)
                u[j] = *(const unsigned int*)(xb + (size_t)(pv[j] & 0x0FFFFFFF) * D + laneoff);
#pragma unroll
            for (int j = 0; j < 8; ++j) {
                int r = ((unsigned)pv[j]) >> 28;   // uniform
                int si = (r < 8) ? r : 8;
                float2v f;
                f.x = b2f_lo(u[j]);
                f.y = b2f_hi(u[j]);
                if (si != cur) {                   // uniform branch
                    if (cur < 8) {
                        *(unsigned int*)((char*)At + at4(nl, cur * D + laneoff)) =
                            f2b(racc.x * inv) | (f2b(racc.y * inv) << 16);
                        wmask |= 1u << cur;
                    }
                    cur = si;
                    racc = f;
                } else {
                    racc += f;
                }
            }
        }
        if (cur < 8) {
            *(unsigned int*)((char*)At + at4(nl, cur * D + laneoff)) =
                f2b(racc.x * inv) | (f2b(racc.y * inv) << 16);
            wmask |= 1u << cur;
        }
        // zero-fill rows for relations with no edges
#pragma unroll
        for (int r = 0; r < 8; ++r)
            if (!(wmask & (1u << r)))
                *(unsigned int*)((char*)At + at4(nl, r * D + laneoff)) = 0u;
        // self columns: copy xb[node] into elems 1024..1151
        unsigned int us = *(const unsigned int*)(xb + (size_t)node * D + laneoff);
        *(unsigned int*)((char*)At + at4(nl, KREL + laneoff)) = us;
    }
    __syncthreads();

    // ======== phase 2: GEMM (no barriers; A from LDS, B from global/L2) ========
    const int l16 = lane & 15;
    const int q   = lane >> 4;       // 0..3
    const int nc0 = w * 32;          // wave's 32 output cols (1M x 4N split)

    float4v acc[2][2] = {};

#pragma unroll
    for (int t = 0; t < KTOT / 64; ++t) {        // 18 steps, fully unrolled
        const int kk = t * 64;
        short8 a[2][2], b[2][2];
#pragma unroll
        for (int ks = 0; ks < 2; ++ks) {
            int c = ks * 4 + q;
#pragma unroll
            for (int mi = 0; mi < 2; ++mi) {
                int r_ = mi * 16 + l16;
                a[ks][mi] = *(const short8*)((const char*)At +
                    r_ * ROWB + kk * 2 + ((c ^ (r_ & 7)) << 4));
            }
#pragma unroll
            for (int ni = 0; ni < 2; ++ni) {
                int o = nc0 + ni * 16 + l16;
                b[ks][ni] = *(const short8*)(Bt + (size_t)o * KTOT + kk + c * 8);
            }
        }
#pragma unroll
        for (int ks = 0; ks < 2; ++ks)
#pragma unroll
            for (int mi = 0; mi < 2; ++mi)
#pragma unroll
                for (int ni = 0; ni < 2; ++ni)
                    acc[mi][ni] = __builtin_amdgcn_mfma_f32_16x16x32_bf16(
                        a[ks][mi], b[ks][ni], acc[mi][ni], 0, 0, 0);
    }

#pragma unroll
    for (int ni = 0; ni < 2; ++ni) {
        int c = nc0 + ni * 16 + l16;
        float bv = bias[c];
#pragma unroll
        for (int mi = 0; mi < 2; ++mi) {
#pragma unroll
            for (int j = 0; j < 4; ++j) {
                int gr = node0 + mi * 16 + q * 4 + j;
                if (gr < Nn)
                    out[(size_t)gr * D + c] = fmaxf(acc[mi][ni][j] + bv, 0.0f);
            }
        }
    }
}

extern "C" void kernel_launch(void* const* d_in, const int* in_sizes, int n_in,
                              void* d_out, int out_size, void* d_ws, size_t ws_size,
                              hipStream_t stream) {
    const float* x      = (const float*)d_in[0];
    const float* W_rel  = (const float*)d_in[1];
    const float* W_self = (const float*)d_in[2];
    const float* W_bias = (const float*)d_in[3];
    const int*   ei     = (const int*)d_in[4];
    const int*   et     = (const int*)d_in[5];

    const int Nn = in_sizes[0] / D;       // 50000
    const int E  = in_sizes[4] / 2;       // 800000
    const int nbkt = (Nn + BRANGE - 1) >> BSHIFT;         // 782
    const int gz   = nbkt * CSTRIDE;
    const int nblk = (Nn + BLK_M - 1) / BLK_M;            // fused blocks (1563)

    // ---- workspace layout (256B aligned chunks) ----
    char* p = (char*)d_ws;
    auto take = [&](size_t bytes) { char* q = p; p += (bytes + 255) & ~(size_t)255; return q; };
    unsigned short* xb   = (unsigned short*)take((size_t)Nn * D * sizeof(unsigned short));
    unsigned short* Bt   = (unsigned short*)take((size_t)128 * KTOT * sizeof(unsigned short));
    int* offsets = (int*)take((size_t)Nn * sizeof(int));
    int* deg     = (int*)take((size_t)Nn * sizeof(int));
    int* gcur    = (int*)take((size_t)gz * sizeof(int));
    int* data    = (int*)take((size_t)nbkt * BCAP * sizeof(int));  // bucket records -> sorted

    const int xb_blocks = (Nn * 32 + 255) / 256;
    const int bt_blocks = (128 * KTOT + 255) / 256;
    const int gz_blocks = (gz + 255) / 256;
    prep_kernel<<<xb_blocks + bt_blocks + gz_blocks, 256, 0, stream>>>(
        x, W_rel, W_self, xb, Bt, gcur, Nn, xb_blocks, bt_blocks, gz);
    coarse_kernel<<<(E + 2047) / 2048, 256, 0, stream>>>(ei, et, gcur, data, E, nbkt);
    fine_kernel<<<nbkt, 256, 0, stream>>>(data, gcur, offsets, deg, Nn);
    fused_kernel<<<nblk, 256, 0, stream>>>(xb, offsets, deg, data, Bt, W_bias,
                                           (float*)d_out, Nn);
}

// Round 6
// 262.558 us; speedup vs baseline: 1.0402x; 1.0402x over previous
//
#include <hip/hip_runtime.h>
#include <hip/hip_bf16.h>

// RGCN layer: out = relu(x @ W_self^T + b + agg/deg)
// Pipeline v16 (5 dispatches): v12 split structure + barrier-free direct-global GEMM
//   1. prep: xb = bf16(x), Bt = bf16([W_rel; W_self^T]), zero bucket cursors
//   2. coarse: edges -> 782 buckets of 64 dst-nodes; 4B packed records
//   3. fine: one block per bucket; LDS hist/scan/scatter -> (dst,rel)-sorted + x8 pad
//   4. aggregate: one wave per node; 8-batched edge loop, flush-on-rel-change -> A
//   5. gemm: 64x128 tile, NO LDS, NO barriers: A/B fragments loaded directly from
//      global (A rows 16x64B full lines; Bt L2-resident), 18 unrolled K-steps,
//      compiler-scheduled vmcnt pipelining, relu+bias epilogue

#define D 128
#define RNUM 8
#define KREL (RNUM * D)      // 1024 — A's row pitch
#define KTOT (KREL + D)      // 1152
#define BLK_M 64

#define BSHIFT 6             // 64 nodes per bucket
#define BRANGE 64
#define BCAP   2048          // slots per bucket region (avg fill ~1250)
#define NBKT_MAX 784
#define CSTRIDE 16           // bucket cursor padding (ints) to spread atomic lines

typedef short short8 __attribute__((ext_vector_type(8)));
typedef float float4v __attribute__((ext_vector_type(4)));
typedef float float2v __attribute__((ext_vector_type(2)));

// fp32 -> bf16 round-nearest-even (bit pattern)
static __device__ __forceinline__ unsigned int f2b(float f) {
    unsigned int u = __float_as_uint(f);
    return (u + 0x7fffu + ((u >> 16) & 1u)) >> 16;
}
static __device__ __forceinline__ float b2f_lo(unsigned int u) {
    return __uint_as_float(u << 16);
}
static __device__ __forceinline__ float b2f_hi(unsigned int u) {
    return __uint_as_float(u & 0xffff0000u);
}

// ---------- prep (3 block ranges): xb | Bt | zero bucket cursors ----------
__global__ void prep_kernel(const float* __restrict__ x,
                            const float* __restrict__ W_rel,
                            const float* __restrict__ W_self,
                            unsigned short* __restrict__ xb,
                            unsigned short* __restrict__ Bt,
                            int* __restrict__ gcur,
                            int Nn, int xb_blocks, int bt_blocks, int gz) {
    if (blockIdx.x < (unsigned)xb_blocks) {
        int t = blockIdx.x * 256 + threadIdx.x;
        int n = t >> 5;              // 32 threads/row, 4 cols each
        int c = (t & 31) * 4;
        if (n >= Nn) return;
        float4 v = *(const float4*)(x + (size_t)n * D + c);
        unsigned int p0 = f2b(v.x) | (f2b(v.y) << 16);
        unsigned int p1 = f2b(v.z) | (f2b(v.w) << 16);
        *(uint2*)(xb + (size_t)n * D + c) = make_uint2(p0, p1);
    } else if (blockIdx.x < (unsigned)(xb_blocks + bt_blocks)) {
        int idx = (blockIdx.x - xb_blocks) * 256 + threadIdx.x;
        if (idx >= 128 * KTOT) return;
        int o = idx / KTOT;
        int k = idx - o * KTOT;
        float v = (k < KREL) ? W_rel[(size_t)k * D + o]   // [r][d][o] flat = k*128+o
                             : W_self[(size_t)o * D + (k - KREL)];
        Bt[idx] = (unsigned short)f2b(v);
    } else {
        int idx = (blockIdx.x - xb_blocks - bt_blocks) * 256 + threadIdx.x;
        if (idx < gz) gcur[idx] = 0;
    }
}

// ---------- coarse: edges -> buckets, block-aggregated reservation ----------
__global__ __launch_bounds__(256) void coarse_kernel(
        const int* __restrict__ ei, const int* __restrict__ et,
        int* __restrict__ gcur, int* __restrict__ data, int E, int nbkt) {
    __shared__ int cnt[NBKT_MAX];
    int t = threadIdx.x;
    for (int i = t; i < nbkt; i += 256) cnt[i] = 0;
    __syncthreads();

    int rec[8], rb[8], rk[8];
    int e0 = blockIdx.x * 2048;
#pragma unroll
    for (int j = 0; j < 8; ++j) {
        int e = e0 + j * 256 + t;
        bool ok = e < E;
        int s = ok ? ei[e] : 0;
        int d = ok ? ei[E + e] : 0;
        int r = ok ? et[e] : 0;
        int bkt = d >> BSHIFT;
        rec[j] = s | ((d & (BRANGE - 1)) << 16) | (r << 22);
        rb[j] = ok ? bkt : -1;
        rk[j] = ok ? atomicAdd(&cnt[bkt], 1) : 0;
    }
    __syncthreads();

    // reserve global space per nonempty bucket; store absolute write base in cnt[]
    for (int i = t; i < nbkt; i += 256) {
        int c = cnt[i];
        if (c) cnt[i] = i * BCAP + atomicAdd(&gcur[i * CSTRIDE], c);
    }
    __syncthreads();

#pragma unroll
    for (int j = 0; j < 8; ++j) {
        if (rb[j] >= 0) {
            int pos = cnt[rb[j]] + rk[j];
            if (pos < (rb[j] + 1) * BCAP)   // capacity guard (never hit on sane data)
                data[pos] = rec[j];
        }
    }
}

// ---------- fine: one block per bucket; LDS hist + scan + in-place scatter ----------
__global__ __launch_bounds__(256) void fine_kernel(
        int* __restrict__ data, const int* __restrict__ gcur,
        int* __restrict__ offsets, int* __restrict__ deg, int Nn) {
    __shared__ int recs[BCAP];            // 8 KB
    __shared__ int hist[BRANGE * RNUM];   // 2 KB: counts, then converted to cursors
    int b = blockIdx.x;
    int t = threadIdx.x;
    int gbase = b * BCAP;
    int cnt = gcur[b * CSTRIDE];
    if (cnt > BCAP) cnt = BCAP;

    for (int i = t; i < BRANGE * RNUM; i += 256) hist[i] = 0;
    __syncthreads();

    // stage records to LDS + per-(node,rel) histogram (LDS atomics)
    for (int i = t; i < cnt; i += 256) {
        int rec = data[gbase + i];
        recs[i] = rec;
        int n = (rec >> 16) & (BRANGE - 1);
        int r = (rec >> 22) & 7;
        atomicAdd(&hist[n * RNUM + r], 1);
    }
    __syncthreads();

    // first wave: per-node padded scan, emit offsets/deg, sentinels, rel cursors
    if (t < BRANGE) {
        int dsum = 0;
#pragma unroll
        for (int r = 0; r < RNUM; ++r) dsum += hist[t * RNUM + r];
        int pad = (dsum + 7) & ~7;
        int x = pad;                       // inclusive scan across 64 lanes
        for (int off = 1; off < 64; off <<= 1) {
            int y = __shfl_up(x, off);
            if (t >= off) x += y;
        }
        int nb = gbase + (x - pad);        // node base (exclusive prefix)
        int n0 = b * BRANGE + t;
        if (n0 < Nn) { offsets[n0] = nb; deg[n0] = dsum; }
        for (int i = dsum; i < pad; ++i)
            data[nb + i] = (int)0xF0000000u;   // sentinel: rel 15
        int q = nb;
#pragma unroll
        for (int r = 0; r < RNUM; ++r) { int c = hist[t * RNUM + r]; hist[t * RNUM + r] = q; q += c; }
    }
    __syncthreads();

    // scatter in place (reads are fully staged in LDS)
    for (int i = t; i < cnt; i += 256) {
        int rec = recs[i];
        int n = (rec >> 16) & (BRANGE - 1);
        int r = (rec >> 22) & 7;
        int pos = atomicAdd(&hist[n * RNUM + r], 1);
        data[pos] = (rec & 0xFFFF) | (r << 28);
    }
}

// ---------- aggregation: one wave per node, rel-sorted flat stream, flush-on-change ----------
__global__ __launch_bounds__(256) void aggregate_kernel(
        const unsigned short* __restrict__ xb,
        const int* __restrict__ offsets,      // node base, multiple of 8
        const int* __restrict__ deg,          // real in-degree
        const int* __restrict__ sorted,       // src | rel<<28, sentinel 0xF0000000 padded
        unsigned short* __restrict__ A,       // [Nn][KREL]
        int Nn) {
    int node = blockIdx.x * 4 + (threadIdx.x >> 6);
    if (node >= Nn) return;
    int lane = threadIdx.x & 63;
    int laneoff = lane * 2;   // bf16-element offset within row

    // wave-uniform SGPR bounds -> uniform loop -> scalar loads of sorted[]
    int b0 = __builtin_amdgcn_readfirstlane(offsets[node]);
    int dg = __builtin_amdgcn_readfirstlane(deg[node]);
    int b1 = b0 + ((dg + 7) & ~7);
    float inv = 1.0f / fmaxf((float)dg, 1.0f);

    unsigned short* arow = A + (size_t)node * KREL + laneoff;

    unsigned wmask = 0;       // which rel rows have been written
    int cur = 8;              // current slot; 8 = trash (sentinels / start)
    float2v racc = {0.0f, 0.0f};

    // b1-b0 is a multiple of 8 by construction: always full 8-wide batches
    for (int e = b0; e < b1; e += 8) {
        int pv[8];
#pragma unroll
        for (int j = 0; j < 8; ++j)
            pv[j] = __builtin_amdgcn_readfirstlane(sorted[e + j]);   // SGPR
        unsigned int u[8];
#pragma unroll
        for (int j = 0; j < 8; ++j)
            u[j] = *(const unsigned int*)(xb + (size_t)(pv[j] & 0x0FFFFFFF) * D + laneoff);
#pragma unroll
        for (int j = 0; j < 8; ++j) {
            int r = ((unsigned)pv[j]) >> 28;          // uniform
            int si = (r < 8) ? r : 8;                 // sentinel -> trash slot
            float2v f;
            f.x = b2f_lo(u[j]);
            f.y = b2f_hi(u[j]);
            if (si != cur) {                          // uniform branch, ~9 taken/node
                if (cur < 8) {
                    *(unsigned int*)(arow + cur * D) =
                        f2b(racc.x * inv) | (f2b(racc.y * inv) << 16);
                    wmask |= 1u << cur;
                }
                cur = si;
                racc = f;
            } else {
                racc += f;
            }
        }
    }
    if (cur < 8) {
        *(unsigned int*)(arow + cur * D) =
            f2b(racc.x * inv) | (f2b(racc.y * inv) << 16);
        wmask |= 1u << cur;
    }
    // zero-fill rows for relations with no edges
#pragma unroll
    for (int r = 0; r < 8; ++r)
        if (!(wmask & (1u << r)))
            *(unsigned int*)(arow + r * D) = 0u;
}

// ---------- GEMM: out[64 x 128 tile] = relu([A|xb] @ Bt^T + b) ----------
// NO LDS, NO barriers. Fragments loaded directly from global; 18 unrolled K-steps.
// Wave (wm,wn): rows wm*32..+31, cols wn*64..+63. Per K=32 window, lane l
// (l16 = l&15, q = l>>4) holds 8 bf16 of row l16 at k = q*8 (canonical 16x16x32 frag).
__global__ __launch_bounds__(256) void gemm_kernel(
        const unsigned short* __restrict__ A,    // [.][KREL]
        const unsigned short* __restrict__ xb,   // [.][D] — self K-columns
        const unsigned short* __restrict__ Bt,   // [128][KTOT]
        const float* __restrict__ bias,
        float* __restrict__ out,
        int Nn) {
    const int tid  = threadIdx.x;
    const int lane = tid & 63;
    const int w    = tid >> 6;
    const int wm   = w & 1;        // 2 m-slots of 32 rows
    const int wn   = w >> 1;       // 2 n-slots of 64 cols
    const int l16  = lane & 15;
    const int q    = lane >> 4;    // 0..3
    const int row0 = blockIdx.x * BLK_M;

    float4v acc[2][4] = {};

    // per-wave fragment base pointers (k-offset q*8 folded in)
    const unsigned short* a0 = A  + (size_t)(row0 + wm * 32 + l16) * KREL + q * 8;
    const unsigned short* x0 = xb + (size_t)(row0 + wm * 32 + l16) * D    + q * 8;
    const unsigned short* bp = Bt + (size_t)(wn * 64 + l16) * KTOT       + q * 8;

#pragma unroll
    for (int t = 0; t < KTOT / 64; ++t) {        // 18 steps, fully unrolled
        const int kk = t * 64;
        short8 a[2][2], b[2][4];
#pragma unroll
        for (int ks = 0; ks < 2; ++ks) {
            const int ko = kk + ks * 32;
#pragma unroll
            for (int mi = 0; mi < 2; ++mi)
                a[ks][mi] = (kk < KREL)
                    ? *(const short8*)(a0 + (size_t)mi * 16 * KREL + ko)
                    : *(const short8*)(x0 + (size_t)mi * 16 * D + (ko - KREL));
#pragma unroll
            for (int ni = 0; ni < 4; ++ni)
                b[ks][ni] = *(const short8*)(bp + (size_t)ni * 16 * KTOT + ko);
        }
#pragma unroll
        for (int ks = 0; ks < 2; ++ks)
#pragma unroll
            for (int mi = 0; mi < 2; ++mi)
#pragma unroll
                for (int ni = 0; ni < 4; ++ni)
                    acc[mi][ni] = __builtin_amdgcn_mfma_f32_16x16x32_bf16(
                        a[ks][mi], b[ks][ni], acc[mi][ni], 0, 0, 0);
    }

#pragma unroll
    for (int ni = 0; ni < 4; ++ni) {
        int c = wn * 64 + ni * 16 + l16;
        float bv = bias[c];
#pragma unroll
        for (int mi = 0; mi < 2; ++mi) {
#pragma unroll
            for (int j = 0; j < 4; ++j) {
                int gr = row0 + wm * 32 + mi * 16 + q * 4 + j;
                if (gr < Nn)
                    out[(size_t)gr * D + c] = fmaxf(acc[mi][ni][j] + bv, 0.0f);
            }
        }
    }
}

extern "C" void kernel_launch(void* const* d_in, const int* in_sizes, int n_in,
                              void* d_out, int out_size, void* d_ws, size_t ws_size,
                              hipStream_t stream) {
    const float* x      = (const float*)d_in[0];
    const float* W_rel  = (const float*)d_in[1];
    const float* W_self = (const float*)d_in[2];
    const float* W_bias = (const float*)d_in[3];
    const int*   ei     = (const int*)d_in[4];
    const int*   et     = (const int*)d_in[5];

    const int Nn = in_sizes[0] / D;       // 50000
    const int E  = in_sizes[4] / 2;       // 800000
    const int npad = ((Nn + BLK_M - 1) / BLK_M) * BLK_M;  // pad rows for tile loads
    const int nbkt = (Nn + BRANGE - 1) >> BSHIFT;         // 782
    const int gz   = nbkt * CSTRIDE;

    // ---- workspace layout (256B aligned chunks) ----
    char* p = (char*)d_ws;
    auto take = [&](size_t bytes) { char* q = p; p += (bytes + 255) & ~(size_t)255; return q; };
    unsigned short* A    = (unsigned short*)take((size_t)npad * KREL * sizeof(unsigned short));
    unsigned short* xb   = (unsigned short*)take((size_t)npad * D * sizeof(unsigned short));
    unsigned short* Bt   = (unsigned short*)take((size_t)128 * KTOT * sizeof(unsigned short));
    int* offsets = (int*)take((size_t)Nn * sizeof(int));
    int* deg     = (int*)take((size_t)Nn * sizeof(int));
    int* gcur    = (int*)take((size_t)gz * sizeof(int));
    int* data    = (int*)take((size_t)nbkt * BCAP * sizeof(int));  // bucket records -> sorted

    const int xb_blocks = (Nn * 32 + 255) / 256;
    const int bt_blocks = (128 * KTOT + 255) / 256;
    const int gz_blocks = (gz + 255) / 256;
    prep_kernel<<<xb_blocks + bt_blocks + gz_blocks, 256, 0, stream>>>(
        x, W_rel, W_self, xb, Bt, gcur, Nn, xb_blocks, bt_blocks, gz);
    coarse_kernel<<<(E + 2047) / 2048, 256, 0, stream>>>(ei, et, gcur, data, E, nbkt);
    fine_kernel<<<nbkt, 256, 0, stream>>>(data, gcur, offsets, deg, Nn);
    aggregate_kernel<<<(Nn + 3) / 4, 256, 0, stream>>>(xb, offsets, deg, data, A, Nn);
    gemm_kernel<<<npad / BLK_M, 256, 0, stream>>>(A, xb, Bt, W_bias, (float*)d_out, Nn);
}

// Round 7
// 233.334 us; speedup vs baseline: 1.1705x; 1.1252x over previous
//
#include <hip/hip_runtime.h>
#include <hip/hip_bf16.h>

// RGCN layer: out = relu(x @ W_self^T + b + agg/deg)
// Pipeline v17 (5 dispatches): v12 split structure + B-resident barrier-free GEMM
//   1. prep: xb = bf16(x), Bt = bf16([W_rel; W_self^T]), zero bucket cursors
//   2. coarse: edges -> 782 buckets of 64 dst-nodes; 4B packed records
//   3. fine: one block per bucket; LDS hist/scan/scatter -> (dst,rel)-sorted + x8 pad
//   4. aggregate: one wave per node; 8-batched edge loop, flush-on-rel-change -> A
//   5. gemm: 128-row strip x 64-col half per block (512 thr, 8 waves).
//      B half staged to LDS ONCE (144 KB, k-major piece layout, conflict-free reads),
//      then 36 unrolled K-windows with NO barriers: per wave {1 global A-load,
//      4 ds_read_b128, 4 MFMA} — independent waves, compiler-pipelined.

#define D 128
#define RNUM 8
#define KREL (RNUM * D)      // 1024 — A's row pitch
#define KTOT (KREL + D)      // 1152
#define BLK_M 128            // rows per gemm block (8 waves x 16)
#define NPIECE (KTOT / 8 * 64)   // 9216 16B pieces in Bs (144 KB)

#define BSHIFT 6             // 64 nodes per bucket
#define BRANGE 64
#define BCAP   2048          // slots per bucket region (avg fill ~1250)
#define NBKT_MAX 784
#define CSTRIDE 16           // bucket cursor padding (ints) to spread atomic lines

typedef short short8 __attribute__((ext_vector_type(8)));
typedef float float4v __attribute__((ext_vector_type(4)));
typedef float float2v __attribute__((ext_vector_type(2)));

// fp32 -> bf16 round-nearest-even (bit pattern)
static __device__ __forceinline__ unsigned int f2b(float f) {
    unsigned int u = __float_as_uint(f);
    return (u + 0x7fffu + ((u >> 16) & 1u)) >> 16;
}
static __device__ __forceinline__ float b2f_lo(unsigned int u) {
    return __uint_as_float(u << 16);
}
static __device__ __forceinline__ float b2f_hi(unsigned int u) {
    return __uint_as_float(u & 0xffff0000u);
}

static __device__ __forceinline__ void gl_lds16(const void* g, void* l) {
    __builtin_amdgcn_global_load_lds(
        (const __attribute__((address_space(1))) unsigned int*)g,
        (__attribute__((address_space(3))) unsigned int*)l, 16, 0, 0);
}

// ---------- prep (3 block ranges): xb | Bt | zero bucket cursors ----------
__global__ void prep_kernel(const float* __restrict__ x,
                            const float* __restrict__ W_rel,
                            const float* __restrict__ W_self,
                            unsigned short* __restrict__ xb,
                            unsigned short* __restrict__ Bt,
                            int* __restrict__ gcur,
                            int Nn, int xb_blocks, int bt_blocks, int gz) {
    if (blockIdx.x < (unsigned)xb_blocks) {
        int t = blockIdx.x * 256 + threadIdx.x;
        int n = t >> 5;              // 32 threads/row, 4 cols each
        int c = (t & 31) * 4;
        if (n >= Nn) return;
        float4 v = *(const float4*)(x + (size_t)n * D + c);
        unsigned int p0 = f2b(v.x) | (f2b(v.y) << 16);
        unsigned int p1 = f2b(v.z) | (f2b(v.w) << 16);
        *(uint2*)(xb + (size_t)n * D + c) = make_uint2(p0, p1);
    } else if (blockIdx.x < (unsigned)(xb_blocks + bt_blocks)) {
        int idx = (blockIdx.x - xb_blocks) * 256 + threadIdx.x;
        if (idx >= 128 * KTOT) return;
        int o = idx / KTOT;
        int k = idx - o * KTOT;
        float v = (k < KREL) ? W_rel[(size_t)k * D + o]   // [r][d][o] flat = k*128+o
                             : W_self[(size_t)o * D + (k - KREL)];
        Bt[idx] = (unsigned short)f2b(v);
    } else {
        int idx = (blockIdx.x - xb_blocks - bt_blocks) * 256 + threadIdx.x;
        if (idx < gz) gcur[idx] = 0;
    }
}

// ---------- coarse: edges -> buckets, block-aggregated reservation ----------
__global__ __launch_bounds__(256) void coarse_kernel(
        const int* __restrict__ ei, const int* __restrict__ et,
        int* __restrict__ gcur, int* __restrict__ data, int E, int nbkt) {
    __shared__ int cnt[NBKT_MAX];
    int t = threadIdx.x;
    for (int i = t; i < nbkt; i += 256) cnt[i] = 0;
    __syncthreads();

    int rec[8], rb[8], rk[8];
    int e0 = blockIdx.x * 2048;
#pragma unroll
    for (int j = 0; j < 8; ++j) {
        int e = e0 + j * 256 + t;
        bool ok = e < E;
        int s = ok ? ei[e] : 0;
        int d = ok ? ei[E + e] : 0;
        int r = ok ? et[e] : 0;
        int bkt = d >> BSHIFT;
        rec[j] = s | ((d & (BRANGE - 1)) << 16) | (r << 22);
        rb[j] = ok ? bkt : -1;
        rk[j] = ok ? atomicAdd(&cnt[bkt], 1) : 0;
    }
    __syncthreads();

    // reserve global space per nonempty bucket; store absolute write base in cnt[]
    for (int i = t; i < nbkt; i += 256) {
        int c = cnt[i];
        if (c) cnt[i] = i * BCAP + atomicAdd(&gcur[i * CSTRIDE], c);
    }
    __syncthreads();

#pragma unroll
    for (int j = 0; j < 8; ++j) {
        if (rb[j] >= 0) {
            int pos = cnt[rb[j]] + rk[j];
            if (pos < (rb[j] + 1) * BCAP)   // capacity guard (never hit on sane data)
                data[pos] = rec[j];
        }
    }
}

// ---------- fine: one block per bucket; LDS hist + scan + in-place scatter ----------
__global__ __launch_bounds__(256) void fine_kernel(
        int* __restrict__ data, const int* __restrict__ gcur,
        int* __restrict__ offsets, int* __restrict__ deg, int Nn) {
    __shared__ int recs[BCAP];            // 8 KB
    __shared__ int hist[BRANGE * RNUM];   // 2 KB: counts, then converted to cursors
    int b = blockIdx.x;
    int t = threadIdx.x;
    int gbase = b * BCAP;
    int cnt = gcur[b * CSTRIDE];
    if (cnt > BCAP) cnt = BCAP;

    for (int i = t; i < BRANGE * RNUM; i += 256) hist[i] = 0;
    __syncthreads();

    // stage records to LDS + per-(node,rel) histogram (LDS atomics)
    for (int i = t; i < cnt; i += 256) {
        int rec = data[gbase + i];
        recs[i] = rec;
        int n = (rec >> 16) & (BRANGE - 1);
        int r = (rec >> 22) & 7;
        atomicAdd(&hist[n * RNUM + r], 1);
    }
    __syncthreads();

    // first wave: per-node padded scan, emit offsets/deg, sentinels, rel cursors
    if (t < BRANGE) {
        int dsum = 0;
#pragma unroll
        for (int r = 0; r < RNUM; ++r) dsum += hist[t * RNUM + r];
        int pad = (dsum + 7) & ~7;
        int x = pad;                       // inclusive scan across 64 lanes
        for (int off = 1; off < 64; off <<= 1) {
            int y = __shfl_up(x, off);
            if (t >= off) x += y;
        }
        int nb = gbase + (x - pad);        // node base (exclusive prefix)
        int n0 = b * BRANGE + t;
        if (n0 < Nn) { offsets[n0] = nb; deg[n0] = dsum; }
        for (int i = dsum; i < pad; ++i)
            data[nb + i] = (int)0xF0000000u;   // sentinel: rel 15
        int q = nb;
#pragma unroll
        for (int r = 0; r < RNUM; ++r) { int c = hist[t * RNUM + r]; hist[t * RNUM + r] = q; q += c; }
    }
    __syncthreads();

    // scatter in place (reads are fully staged in LDS)
    for (int i = t; i < cnt; i += 256) {
        int rec = recs[i];
        int n = (rec >> 16) & (BRANGE - 1);
        int r = (rec >> 22) & 7;
        int pos = atomicAdd(&hist[n * RNUM + r], 1);
        data[pos] = (rec & 0xFFFF) | (r << 28);
    }
}

// ---------- aggregation: one wave per node, rel-sorted flat stream, flush-on-change ----------
__global__ __launch_bounds__(256) void aggregate_kernel(
        const unsigned short* __restrict__ xb,
        const int* __restrict__ offsets,      // node base, multiple of 8
        const int* __restrict__ deg,          // real in-degree
        const int* __restrict__ sorted,       // src | rel<<28, sentinel 0xF0000000 padded
        unsigned short* __restrict__ A,       // [Nn][KREL]
        int Nn) {
    int node = blockIdx.x * 4 + (threadIdx.x >> 6);
    if (node >= Nn) return;
    int lane = threadIdx.x & 63;
    int laneoff = lane * 2;   // bf16-element offset within row

    // wave-uniform SGPR bounds -> uniform loop -> scalar loads of sorted[]
    int b0 = __builtin_amdgcn_readfirstlane(offsets[node]);
    int dg = __builtin_amdgcn_readfirstlane(deg[node]);
    int b1 = b0 + ((dg + 7) & ~7);
    float inv = 1.0f / fmaxf((float)dg, 1.0f);

    unsigned short* arow = A + (size_t)node * KREL + laneoff;

    unsigned wmask = 0;       // which rel rows have been written
    int cur = 8;              // current slot; 8 = trash (sentinels / start)
    float2v racc = {0.0f, 0.0f};

    // b1-b0 is a multiple of 8 by construction: always full 8-wide batches
    for (int e = b0; e < b1; e += 8) {
        int pv[8];
#pragma unroll
        for (int j = 0; j < 8; ++j)
            pv[j] = __builtin_amdgcn_readfirstlane(sorted[e + j]);   // SGPR
        unsigned int u[8];
#pragma unroll
        for (int j = 0; j < 8; ++j)
            u[j] = *(const unsigned int*)(xb + (size_t)(pv[j] & 0x0FFFFFFF) * D + laneoff);
#pragma unroll
        for (int j = 0; j < 8; ++j) {
            int r = ((unsigned)pv[j]) >> 28;          // uniform
            int si = (r < 8) ? r : 8;                 // sentinel -> trash slot
            float2v f;
            f.x = b2f_lo(u[j]);
            f.y = b2f_hi(u[j]);
            if (si != cur) {                          // uniform branch, ~9 taken/node
                if (cur < 8) {
                    *(unsigned int*)(arow + cur * D) =
                        f2b(racc.x * inv) | (f2b(racc.y * inv) << 16);
                    wmask |= 1u << cur;
                }
                cur = si;
                racc = f;
            } else {
                racc += f;
            }
        }
    }
    if (cur < 8) {
        *(unsigned int*)(arow + cur * D) =
            f2b(racc.x * inv) | (f2b(racc.y * inv) << 16);
        wmask |= 1u << cur;
    }
    // zero-fill rows for relations with no edges
#pragma unroll
    for (int r = 0; r < 8; ++r)
        if (!(wmask & (1u << r)))
            *(unsigned int*)(arow + r * D) = 0u;
}

// ---------- GEMM: out[128-row strip, 64-col half] = relu([A|xb] @ Bt^T + b) ----------
// Bs staged ONCE (144 KB, k-major pieces: piece qk=k/8 of col c at flat [qk*64+c]).
// Then 36 K=32 windows, NO barriers: per wave {1 A-load, 4 ds_read_b128, 4 MFMA}.
__global__ __launch_bounds__(512, 1) void gemm_kernel(
        const unsigned short* __restrict__ A,    // [.][KREL]
        const unsigned short* __restrict__ xb,   // [.][D] — self K-columns
        const unsigned short* __restrict__ Bt,   // [128][KTOT]
        const float* __restrict__ bias,
        float* __restrict__ out,
        int Nn) {
    __shared__ unsigned short Bs[NPIECE * 8];    // 147456 B

    const int tid  = threadIdx.x;
    const int lane = tid & 63;
    const int w    = tid >> 6;         // 0..7: wave = 16-row slice
    const int l16  = lane & 15;
    const int q    = lane >> 4;        // 0..3: 16B piece within K=32 window
    const int half   = blockIdx.x & 1;
    const int mstrip = blockIdx.x >> 1;
    const int col0   = half * 64;
    const int row0w  = mstrip * BLK_M + w * 16;

    // ---- stage B half into LDS (18 chunks x 512 lanes x 16B) ----
#pragma unroll
    for (int c = 0; c < NPIECE / 512; ++c) {     // 18
        int g = c * 512 + w * 64 + lane;         // piece index
        int col = g & 63;
        int qk  = g >> 6;                        // 0..143 -> k = qk*8
        const unsigned short* src = Bt + (size_t)(col0 + col) * KTOT + qk * 8;
        gl_lds16(src, &Bs[(size_t)(c * 512 + w * 64) * 8]);
    }
    __syncthreads();                             // drains vmcnt, Bs ready

    // ---- barrier-free main loop: 36 K=32 windows ----
    const unsigned short* a0 = A  + (size_t)(row0w + l16) * KREL + q * 8;
    const unsigned short* x0 = xb + (size_t)(row0w + l16) * D    + q * 8;
    const short8* bsv = (const short8*)Bs;

    float4v acc[4] = {};

#pragma unroll
    for (int m = 0; m < KTOT / 32; ++m) {        // 36, fully unrolled
        short8 a = (m < 32) ? *(const short8*)(a0 + m * 32)
                            : *(const short8*)(x0 + (m - 32) * 32);
        int qk = m * 4 + q;
        short8 b[4];
#pragma unroll
        for (int ni = 0; ni < 4; ++ni)
            b[ni] = bsv[qk * 64 + ni * 16 + l16];
#pragma unroll
        for (int ni = 0; ni < 4; ++ni)
            acc[ni] = __builtin_amdgcn_mfma_f32_16x16x32_bf16(a, b[ni], acc[ni], 0, 0, 0);
    }

    // ---- epilogue: bias + relu ----
#pragma unroll
    for (int ni = 0; ni < 4; ++ni) {
        int c = col0 + ni * 16 + l16;
        float bv = bias[c];
#pragma unroll
        for (int j = 0; j < 4; ++j) {
            int gr = row0w + q * 4 + j;
            if (gr < Nn)
                out[(size_t)gr * D + c] = fmaxf(acc[ni][j] + bv, 0.0f);
        }
    }
}

extern "C" void kernel_launch(void* const* d_in, const int* in_sizes, int n_in,
                              void* d_out, int out_size, void* d_ws, size_t ws_size,
                              hipStream_t stream) {
    const float* x      = (const float*)d_in[0];
    const float* W_rel  = (const float*)d_in[1];
    const float* W_self = (const float*)d_in[2];
    const float* W_bias = (const float*)d_in[3];
    const int*   ei     = (const int*)d_in[4];
    const int*   et     = (const int*)d_in[5];

    const int Nn = in_sizes[0] / D;       // 50000
    const int E  = in_sizes[4] / 2;       // 800000
    const int npad = ((Nn + BLK_M - 1) / BLK_M) * BLK_M;  // pad rows for tile loads
    const int nbkt = (Nn + BRANGE - 1) >> BSHIFT;         // 782
    const int gz   = nbkt * CSTRIDE;
    const int nstrips = npad / BLK_M;                     // 391

    // ---- workspace layout (256B aligned chunks) ----
    char* p = (char*)d_ws;
    auto take = [&](size_t bytes) { char* q = p; p += (bytes + 255) & ~(size_t)255; return q; };
    unsigned short* A    = (unsigned short*)take((size_t)npad * KREL * sizeof(unsigned short));
    unsigned short* xb   = (unsigned short*)take((size_t)npad * D * sizeof(unsigned short));
    unsigned short* Bt   = (unsigned short*)take((size_t)128 * KTOT * sizeof(unsigned short));
    int* offsets = (int*)take((size_t)Nn * sizeof(int));
    int* deg     = (int*)take((size_t)Nn * sizeof(int));
    int* gcur    = (int*)take((size_t)gz * sizeof(int));
    int* data    = (int*)take((size_t)nbkt * BCAP * sizeof(int));  // bucket records -> sorted

    const int xb_blocks = (Nn * 32 + 255) / 256;
    const int bt_blocks = (128 * KTOT + 255) / 256;
    const int gz_blocks = (gz + 255) / 256;
    prep_kernel<<<xb_blocks + bt_blocks + gz_blocks, 256, 0, stream>>>(
        x, W_rel, W_self, xb, Bt, gcur, Nn, xb_blocks, bt_blocks, gz);
    coarse_kernel<<<(E + 2047) / 2048, 256, 0, stream>>>(ei, et, gcur, data, E, nbkt);
    fine_kernel<<<nbkt, 256, 0, stream>>>(data, gcur, offsets, deg, Nn);
    aggregate_kernel<<<(Nn + 3) / 4, 256, 0, stream>>>(xb, offsets, deg, data, A, Nn);
    gemm_kernel<<<nstrips * 2, 512, 0, stream>>>(A, xb, Bt, W_bias, (float*)d_out, Nn);
}

// Round 8
// 216.813 us; speedup vs baseline: 1.2597x; 1.0762x over previous
//
#include <hip/hip_runtime.h>
#include <hip/hip_bf16.h>

// RGCN layer: out = relu(x @ W_self^T + b + agg/deg)
// Pipeline v18 (5 dispatches): GEMM-FIRST restructure — A matrix eliminated.
//   Z[n, 0..1151] = xb[n] @ [W_0|...|W_7|W_self]  (per-relation transform of ALL nodes)
//   out[dst] = relu(Z[dst,1024..] + b + (1/deg) Σ_edges Z[src_e, rel_e*128..])
//   1. prep: xb = bf16(x), Wcol = bf16 col-major weights [1152][128], zero cursors
//   2. coarse: edges -> 782 buckets of 64 dst-nodes; 4B packed records
//   3. fine: one block per bucket; LDS hist/scan/scatter -> (dst,rel)-sorted + x8 pad
//   4. zgemm: Z = xb @ Wcol. K=128 (no K loop): per wave xb in 4 reg-frags loaded
//      once; W staged in 4 x 72KB LDS chunks (XOR piece-swizzle); swapped-operand
//      MFMA so each lane stores 4 consecutive Z cols (8B packed stores).
//   5. gather: one wave per node; 8-batched scalar edge stream, racc += Z row
//      (NO rel tracking), epilogue out = relu(Zself + bias + racc*inv) direct.

#define D 128
#define RNUM 8
#define KREL (RNUM * D)      // 1024
#define KTOT (KREL + D)      // 1152 — Z row pitch
#define CCHUNK 288           // zgemm col-chunk (4 chunks of 288 = 1152)
#define NBLK_N 128           // zgemm nodes per block (8 waves x 16)

#define BSHIFT 6             // 64 nodes per bucket
#define BRANGE 64
#define BCAP   2048          // slots per bucket region (avg fill ~1250)
#define NBKT_MAX 784
#define CSTRIDE 16           // bucket cursor padding (ints) to spread atomic lines

typedef short short8 __attribute__((ext_vector_type(8)));
typedef float float4v __attribute__((ext_vector_type(4)));
typedef float float2v __attribute__((ext_vector_type(2)));

// fp32 -> bf16 round-nearest-even (bit pattern)
static __device__ __forceinline__ unsigned int f2b(float f) {
    unsigned int u = __float_as_uint(f);
    return (u + 0x7fffu + ((u >> 16) & 1u)) >> 16;
}
static __device__ __forceinline__ float b2f_lo(unsigned int u) {
    return __uint_as_float(u << 16);
}
static __device__ __forceinline__ float b2f_hi(unsigned int u) {
    return __uint_as_float(u & 0xffff0000u);
}

static __device__ __forceinline__ void gl_lds16(const void* g, void* l) {
    __builtin_amdgcn_global_load_lds(
        (const __attribute__((address_space(1))) unsigned int*)g,
        (__attribute__((address_space(3))) unsigned int*)l, 16, 0, 0);
}

// ---------- prep (3 block ranges): xb | Wcol | zero bucket cursors ----------
__global__ void prep_kernel(const float* __restrict__ x,
                            const float* __restrict__ W_rel,
                            const float* __restrict__ W_self,
                            unsigned short* __restrict__ xb,
                            unsigned short* __restrict__ Wcol,
                            int* __restrict__ gcur,
                            int Nn, int xb_blocks, int wc_blocks, int gz) {
    if (blockIdx.x < (unsigned)xb_blocks) {
        int t = blockIdx.x * 256 + threadIdx.x;
        int n = t >> 5;              // 32 threads/row, 4 cols each
        int c = (t & 31) * 4;
        if (n >= Nn) return;
        float4 v = *(const float4*)(x + (size_t)n * D + c);
        unsigned int p0 = f2b(v.x) | (f2b(v.y) << 16);
        unsigned int p1 = f2b(v.z) | (f2b(v.w) << 16);
        *(uint2*)(xb + (size_t)n * D + c) = make_uint2(p0, p1);
    } else if (blockIdx.x < (unsigned)(xb_blocks + wc_blocks)) {
        int idx = (blockIdx.x - xb_blocks) * 256 + threadIdx.x;
        if (idx >= KTOT * D) return;
        int c = idx >> 7;            // output col 0..1151
        int k = idx & 127;           // input dim
        float v = (c < KREL)
            ? W_rel[(size_t)((c >> 7) * D + k) * D + (c & 127)]   // W_rel[r][k][o]
            : W_self[(size_t)(c - KREL) * D + k];                 // W_self[o][k]
        Wcol[idx] = (unsigned short)f2b(v);
    } else {
        int idx = (blockIdx.x - xb_blocks - wc_blocks) * 256 + threadIdx.x;
        if (idx < gz) gcur[idx] = 0;
    }
}

// ---------- coarse: edges -> buckets, block-aggregated reservation ----------
__global__ __launch_bounds__(256) void coarse_kernel(
        const int* __restrict__ ei, const int* __restrict__ et,
        int* __restrict__ gcur, int* __restrict__ data, int E, int nbkt) {
    __shared__ int cnt[NBKT_MAX];
    int t = threadIdx.x;
    for (int i = t; i < nbkt; i += 256) cnt[i] = 0;
    __syncthreads();

    int rec[8], rb[8], rk[8];
    int e0 = blockIdx.x * 2048;
#pragma unroll
    for (int j = 0; j < 8; ++j) {
        int e = e0 + j * 256 + t;
        bool ok = e < E;
        int s = ok ? ei[e] : 0;
        int d = ok ? ei[E + e] : 0;
        int r = ok ? et[e] : 0;
        int bkt = d >> BSHIFT;
        rec[j] = s | ((d & (BRANGE - 1)) << 16) | (r << 22);
        rb[j] = ok ? bkt : -1;
        rk[j] = ok ? atomicAdd(&cnt[bkt], 1) : 0;
    }
    __syncthreads();

    // reserve global space per nonempty bucket; store absolute write base in cnt[]
    for (int i = t; i < nbkt; i += 256) {
        int c = cnt[i];
        if (c) cnt[i] = i * BCAP + atomicAdd(&gcur[i * CSTRIDE], c);
    }
    __syncthreads();

#pragma unroll
    for (int j = 0; j < 8; ++j) {
        if (rb[j] >= 0) {
            int pos = cnt[rb[j]] + rk[j];
            if (pos < (rb[j] + 1) * BCAP)   // capacity guard (never hit on sane data)
                data[pos] = rec[j];
        }
    }
}

// ---------- fine: one block per bucket; LDS hist + scan + in-place scatter ----------
__global__ __launch_bounds__(256) void fine_kernel(
        int* __restrict__ data, const int* __restrict__ gcur,
        int* __restrict__ offsets, int* __restrict__ deg, int Nn) {
    __shared__ int recs[BCAP];            // 8 KB
    __shared__ int hist[BRANGE * RNUM];   // 2 KB: counts, then converted to cursors
    int b = blockIdx.x;
    int t = threadIdx.x;
    int gbase = b * BCAP;
    int cnt = gcur[b * CSTRIDE];
    if (cnt > BCAP) cnt = BCAP;

    for (int i = t; i < BRANGE * RNUM; i += 256) hist[i] = 0;
    __syncthreads();

    // stage records to LDS + per-(node,rel) histogram (LDS atomics)
    for (int i = t; i < cnt; i += 256) {
        int rec = data[gbase + i];
        recs[i] = rec;
        int n = (rec >> 16) & (BRANGE - 1);
        int r = (rec >> 22) & 7;
        atomicAdd(&hist[n * RNUM + r], 1);
    }
    __syncthreads();

    // first wave: per-node padded scan, emit offsets/deg, sentinels, rel cursors
    if (t < BRANGE) {
        int dsum = 0;
#pragma unroll
        for (int r = 0; r < RNUM; ++r) dsum += hist[t * RNUM + r];
        int pad = (dsum + 7) & ~7;
        int x = pad;                       // inclusive scan across 64 lanes
        for (int off = 1; off < 64; off <<= 1) {
            int y = __shfl_up(x, off);
            if (t >= off) x += y;
        }
        int nb = gbase + (x - pad);        // node base (exclusive prefix)
        int n0 = b * BRANGE + t;
        if (n0 < Nn) { offsets[n0] = nb; deg[n0] = dsum; }
        for (int i = dsum; i < pad; ++i)
            data[nb + i] = (int)0xF0000000u;   // sentinel: rel 15, src 0
        int q = nb;
#pragma unroll
        for (int r = 0; r < RNUM; ++r) { int c = hist[t * RNUM + r]; hist[t * RNUM + r] = q; q += c; }
    }
    __syncthreads();

    // scatter in place (reads are fully staged in LDS)
    for (int i = t; i < cnt; i += 256) {
        int rec = recs[i];
        int n = (rec >> 16) & (BRANGE - 1);
        int r = (rec >> 22) & 7;
        int pos = atomicAdd(&hist[n * RNUM + r], 1);
        data[pos] = (rec & 0xFFFF) | (r << 28);
    }
}

// ---------- zgemm: Z[n][c] = xb[n] @ Wcol[c], K=128, no K-loop ----------
// 8 waves x 16 nodes; 4 col-chunks of 288, W chunk in 72KB LDS (piece-XOR swizzle).
// Swapped operands: A-frag = W rows (c dim), B-frag = node xb (in registers).
__global__ __launch_bounds__(512) void zgemm_kernel(
        const unsigned short* __restrict__ xb,    // [npad][128]
        const unsigned short* __restrict__ Wcol,  // [1152][128]
        unsigned short* __restrict__ Z) {         // [npad][1152]
    __shared__ unsigned short Ws[CCHUNK * 128];   // 73728 B

    const int tid  = threadIdx.x;
    const int lane = tid & 63;
    const int w    = tid >> 6;
    const int l16  = lane & 15;
    const int q    = lane >> 4;      // 0..3
    const int n    = blockIdx.x * NBLK_N + w * 16 + l16;   // this lane's node

    // xb B-frags: K=128 = 4 windows of 32, loaded ONCE into registers
    short8 xq[4];
#pragma unroll
    for (int kw = 0; kw < 4; ++kw)
        xq[kw] = *(const short8*)(xb + (size_t)n * D + kw * 32 + q * 8);

    for (int ch = 0; ch < 4; ++ch) {
        const int c0 = ch * CCHUNK;
        // stage W chunk: 4608 16B pieces; LDS slot (c,p) holds source piece p^(c&15)
#pragma unroll
        for (int i = 0; i < 9; ++i) {
            int s = i * 512 + w * 64 + lane;
            int c = s >> 4;
            int p = (s & 15) ^ (c & 15);
            gl_lds16(Wcol + (size_t)(c0 + c) * D + p * 8,
                     &Ws[(size_t)(i * 512 + w * 64) * 8]);
        }
        asm volatile("s_waitcnt vmcnt(0)" ::: "memory");
        __builtin_amdgcn_s_barrier();

        float4v acc[18] = {};
#pragma unroll
        for (int cg = 0; cg < 18; ++cg) {
#pragma unroll
            for (int kw = 0; kw < 4; ++kw) {
                // A-frag: row c = cg*16+l16 (c&15 == l16), logical piece kw*4+q
                short8 a = *(const short8*)(
                    &Ws[(((cg * 16 + l16) << 4) + ((kw * 4 + q) ^ l16)) * 8]);
                acc[cg] = __builtin_amdgcn_mfma_f32_16x16x32_bf16(
                    a, xq[kw], acc[cg], 0, 0, 0);
            }
        }
        // store: lane holds node n, cols c0 + cg*16 + q*4 .. +3 (4 consecutive bf16)
#pragma unroll
        for (int cg = 0; cg < 18; ++cg) {
            unsigned int lo = f2b(acc[cg][0]) | (f2b(acc[cg][1]) << 16);
            unsigned int hi = f2b(acc[cg][2]) | (f2b(acc[cg][3]) << 16);
            *(uint2*)(Z + (size_t)n * KTOT + c0 + cg * 16 + q * 4) = make_uint2(lo, hi);
        }
        __builtin_amdgcn_s_barrier();    // Ws reads done before next chunk's stage
    }
}

// ---------- gather: one wave per node; racc += Z[src,rel] rows; direct out ----------
__global__ __launch_bounds__(256) void gather_kernel(
        const unsigned short* __restrict__ Z,     // [npad][1152]
        const int* __restrict__ offsets,          // node base, multiple of 8
        const int* __restrict__ deg,              // real in-degree
        const int* __restrict__ sorted,           // src | rel<<28, sentinel-padded
        const float* __restrict__ bias,
        float* __restrict__ out,
        int Nn) {
    int node = blockIdx.x * 4 + (threadIdx.x >> 6);
    if (node >= Nn) return;
    int lane = threadIdx.x & 63;
    int laneoff = lane * 2;   // bf16-element offset within a 128-wide row

    int b0 = __builtin_amdgcn_readfirstlane(offsets[node]);
    int dg = __builtin_amdgcn_readfirstlane(deg[node]);
    float inv = 1.0f / fmaxf((float)dg, 1.0f);
    int bulk = dg & ~7;
    int rem  = dg & 7;

    float2v racc = {0.0f, 0.0f};

    // full batches: no sentinels, unconditional adds
    for (int e = b0; e < b0 + bulk; e += 8) {
        int pv[8];
#pragma unroll
        for (int j = 0; j < 8; ++j)
            pv[j] = __builtin_amdgcn_readfirstlane(sorted[e + j]);   // SGPR
        unsigned int u[8];
#pragma unroll
        for (int j = 0; j < 8; ++j) {
            int src = pv[j] & 0xFFFF;
            int rel = (((unsigned)pv[j]) >> 28) & 7;
            u[j] = *(const unsigned int*)(Z + (size_t)src * KTOT + rel * D + laneoff);
        }
#pragma unroll
        for (int j = 0; j < 8; ++j) {
            racc.x += b2f_lo(u[j]);
            racc.y += b2f_hi(u[j]);
        }
    }
    // tail batch: rem real edges + sentinels (guarded by j < rem, uniform)
    if (rem) {
        int e = b0 + bulk;
        int pv[8];
#pragma unroll
        for (int j = 0; j < 8; ++j)
            pv[j] = __builtin_amdgcn_readfirstlane(sorted[e + j]);
        unsigned int u[8];
#pragma unroll
        for (int j = 0; j < 8; ++j) {
            int src = pv[j] & 0xFFFF;
            int rel = (((unsigned)pv[j]) >> 28) & 7;
            u[j] = *(const unsigned int*)(Z + (size_t)src * KTOT + rel * D + laneoff);
        }
#pragma unroll
        for (int j = 0; j < 8; ++j) {
            if (j < rem) {
                racc.x += b2f_lo(u[j]);
                racc.y += b2f_hi(u[j]);
            }
        }
    }

    // epilogue: out = relu(Z_self + bias + racc/deg)
    unsigned int zs = *(const unsigned int*)(Z + (size_t)node * KTOT + KREL + laneoff);
    float bx = bias[laneoff];
    float by = bias[laneoff + 1];
    float o0 = fmaxf(b2f_lo(zs) + bx + racc.x * inv, 0.0f);
    float o1 = fmaxf(b2f_hi(zs) + by + racc.y * inv, 0.0f);
    *(float2*)(out + (size_t)node * D + laneoff) = make_float2(o0, o1);
}

extern "C" void kernel_launch(void* const* d_in, const int* in_sizes, int n_in,
                              void* d_out, int out_size, void* d_ws, size_t ws_size,
                              hipStream_t stream) {
    const float* x      = (const float*)d_in[0];
    const float* W_rel  = (const float*)d_in[1];
    const float* W_self = (const float*)d_in[2];
    const float* W_bias = (const float*)d_in[3];
    const int*   ei     = (const int*)d_in[4];
    const int*   et     = (const int*)d_in[5];

    const int Nn = in_sizes[0] / D;       // 50000
    const int E  = in_sizes[4] / 2;       // 800000
    const int npad = ((Nn + NBLK_N - 1) / NBLK_N) * NBLK_N;   // 50048
    const int nbkt = (Nn + BRANGE - 1) >> BSHIFT;             // 782
    const int gz   = nbkt * CSTRIDE;

    // ---- workspace layout (256B aligned chunks) ----
    char* p = (char*)d_ws;
    auto take = [&](size_t bytes) { char* q = p; p += (bytes + 255) & ~(size_t)255; return q; };
    unsigned short* Z    = (unsigned short*)take((size_t)npad * KTOT * sizeof(unsigned short));
    unsigned short* xb   = (unsigned short*)take((size_t)npad * D * sizeof(unsigned short));
    unsigned short* Wcol = (unsigned short*)take((size_t)KTOT * D * sizeof(unsigned short));
    int* offsets = (int*)take((size_t)Nn * sizeof(int));
    int* deg     = (int*)take((size_t)Nn * sizeof(int));
    int* gcur    = (int*)take((size_t)gz * sizeof(int));
    int* data    = (int*)take((size_t)nbkt * BCAP * sizeof(int));  // bucket records -> sorted

    const int xb_blocks = (Nn * 32 + 255) / 256;
    const int wc_blocks = (KTOT * D + 255) / 256;
    const int gz_blocks = (gz + 255) / 256;
    prep_kernel<<<xb_blocks + wc_blocks + gz_blocks, 256, 0, stream>>>(
        x, W_rel, W_self, xb, Wcol, gcur, Nn, xb_blocks, wc_blocks, gz);
    coarse_kernel<<<(E + 2047) / 2048, 256, 0, stream>>>(ei, et, gcur, data, E, nbkt);
    fine_kernel<<<nbkt, 256, 0, stream>>>(data, gcur, offsets, deg, Nn);
    zgemm_kernel<<<npad / NBLK_N, 512, 0, stream>>>(xb, Wcol, Z);
    gather_kernel<<<(Nn + 3) / 4, 256, 0, stream>>>(Z, offsets, deg, data, W_bias,
                                                    (float*)d_out, Nn);
}

// Round 9
// 211.463 us; speedup vs baseline: 1.2915x; 1.0253x over previous
//
#include <hip/hip_runtime.h>
#include <hip/hip_bf16.h>

// RGCN layer: out = relu(x @ W_self^T + b + agg/deg)
// Pipeline v19 (5 dispatches): v18 GEMM-first structure + flattened zgemm
//   Z[n, 0..1151] = xb[n] @ [W_0|...|W_7|W_self];  out = relu(Zself + b + avg(Z[src,rel]))
//   1. prep: xb = bf16(x), Wcol = bf16 col-major weights [1152][128], zero cursors
//   2. coarse: edges -> 782 buckets of 64 dst-nodes; 4B packed records
//   3. fine: one block per bucket; LDS hist/scan/scatter -> (dst,rel)-sorted + x8 pad
//   4. zgemm: grid (18 col-chunks x 782 node-strips); per block: 64 nodes x 64 cols,
//      16KB LDS W-chunk (XOR piece-swizzle), ONE barrier, 16 MFMA/wave, packed stores.
//      No chunk loop -> no vmcnt(0) store-drain serialization; ~8 blocks/CU.
//   5. gather: one wave per node; 8-batched scalar edge stream, racc += Z row,
//      epilogue out = relu(Zself + bias + racc*inv) direct.

#define D 128
#define RNUM 8
#define KREL (RNUM * D)      // 1024
#define KTOT (KREL + D)      // 1152 — Z row pitch
#define ZCH 64               // zgemm cols per block
#define ZNB 64               // zgemm nodes per block (4 waves x 16)

#define BSHIFT 6             // 64 nodes per bucket
#define BRANGE 64
#define BCAP   2048          // slots per bucket region (avg fill ~1250)
#define NBKT_MAX 784
#define CSTRIDE 16           // bucket cursor padding (ints) to spread atomic lines

typedef short short8 __attribute__((ext_vector_type(8)));
typedef float float4v __attribute__((ext_vector_type(4)));
typedef float float2v __attribute__((ext_vector_type(2)));

// fp32 -> bf16 round-nearest-even (bit pattern)
static __device__ __forceinline__ unsigned int f2b(float f) {
    unsigned int u = __float_as_uint(f);
    return (u + 0x7fffu + ((u >> 16) & 1u)) >> 16;
}
static __device__ __forceinline__ float b2f_lo(unsigned int u) {
    return __uint_as_float(u << 16);
}
static __device__ __forceinline__ float b2f_hi(unsigned int u) {
    return __uint_as_float(u & 0xffff0000u);
}

static __device__ __forceinline__ void gl_lds16(const void* g, void* l) {
    __builtin_amdgcn_global_load_lds(
        (const __attribute__((address_space(1))) unsigned int*)g,
        (__attribute__((address_space(3))) unsigned int*)l, 16, 0, 0);
}

// ---------- prep (3 block ranges): xb | Wcol | zero bucket cursors ----------
__global__ void prep_kernel(const float* __restrict__ x,
                            const float* __restrict__ W_rel,
                            const float* __restrict__ W_self,
                            unsigned short* __restrict__ xb,
                            unsigned short* __restrict__ Wcol,
                            int* __restrict__ gcur,
                            int Nn, int xb_blocks, int wc_blocks, int gz) {
    if (blockIdx.x < (unsigned)xb_blocks) {
        int t = blockIdx.x * 256 + threadIdx.x;
        int n = t >> 5;              // 32 threads/row, 4 cols each
        int c = (t & 31) * 4;
        if (n >= Nn) return;
        float4 v = *(const float4*)(x + (size_t)n * D + c);
        unsigned int p0 = f2b(v.x) | (f2b(v.y) << 16);
        unsigned int p1 = f2b(v.z) | (f2b(v.w) << 16);
        *(uint2*)(xb + (size_t)n * D + c) = make_uint2(p0, p1);
    } else if (blockIdx.x < (unsigned)(xb_blocks + wc_blocks)) {
        int idx = (blockIdx.x - xb_blocks) * 256 + threadIdx.x;
        if (idx >= KTOT * D) return;
        int c = idx >> 7;            // output col 0..1151
        int k = idx & 127;           // input dim
        float v = (c < KREL)
            ? W_rel[(size_t)((c >> 7) * D + k) * D + (c & 127)]   // W_rel[r][k][o]
            : W_self[(size_t)(c - KREL) * D + k];                 // W_self[o][k]
        Wcol[idx] = (unsigned short)f2b(v);
    } else {
        int idx = (blockIdx.x - xb_blocks - wc_blocks) * 256 + threadIdx.x;
        if (idx < gz) gcur[idx] = 0;
    }
}

// ---------- coarse: edges -> buckets, block-aggregated reservation ----------
__global__ __launch_bounds__(256) void coarse_kernel(
        const int* __restrict__ ei, const int* __restrict__ et,
        int* __restrict__ gcur, int* __restrict__ data, int E, int nbkt) {
    __shared__ int cnt[NBKT_MAX];
    int t = threadIdx.x;
    for (int i = t; i < nbkt; i += 256) cnt[i] = 0;
    __syncthreads();

    int rec[8], rb[8], rk[8];
    int e0 = blockIdx.x * 2048;
#pragma unroll
    for (int j = 0; j < 8; ++j) {
        int e = e0 + j * 256 + t;
        bool ok = e < E;
        int s = ok ? ei[e] : 0;
        int d = ok ? ei[E + e] : 0;
        int r = ok ? et[e] : 0;
        int bkt = d >> BSHIFT;
        rec[j] = s | ((d & (BRANGE - 1)) << 16) | (r << 22);
        rb[j] = ok ? bkt : -1;
        rk[j] = ok ? atomicAdd(&cnt[bkt], 1) : 0;
    }
    __syncthreads();

    // reserve global space per nonempty bucket; store absolute write base in cnt[]
    for (int i = t; i < nbkt; i += 256) {
        int c = cnt[i];
        if (c) cnt[i] = i * BCAP + atomicAdd(&gcur[i * CSTRIDE], c);
    }
    __syncthreads();

#pragma unroll
    for (int j = 0; j < 8; ++j) {
        if (rb[j] >= 0) {
            int pos = cnt[rb[j]] + rk[j];
            if (pos < (rb[j] + 1) * BCAP)   // capacity guard (never hit on sane data)
                data[pos] = rec[j];
        }
    }
}

// ---------- fine: one block per bucket; LDS hist + scan + in-place scatter ----------
__global__ __launch_bounds__(256) void fine_kernel(
        int* __restrict__ data, const int* __restrict__ gcur,
        int* __restrict__ offsets, int* __restrict__ deg, int Nn) {
    __shared__ int recs[BCAP];            // 8 KB
    __shared__ int hist[BRANGE * RNUM];   // 2 KB: counts, then converted to cursors
    int b = blockIdx.x;
    int t = threadIdx.x;
    int gbase = b * BCAP;
    int cnt = gcur[b * CSTRIDE];
    if (cnt > BCAP) cnt = BCAP;

    for (int i = t; i < BRANGE * RNUM; i += 256) hist[i] = 0;
    __syncthreads();

    // stage records to LDS + per-(node,rel) histogram (LDS atomics)
    for (int i = t; i < cnt; i += 256) {
        int rec = data[gbase + i];
        recs[i] = rec;
        int n = (rec >> 16) & (BRANGE - 1);
        int r = (rec >> 22) & 7;
        atomicAdd(&hist[n * RNUM + r], 1);
    }
    __syncthreads();

    // first wave: per-node padded scan, emit offsets/deg, sentinels, rel cursors
    if (t < BRANGE) {
        int dsum = 0;
#pragma unroll
        for (int r = 0; r < RNUM; ++r) dsum += hist[t * RNUM + r];
        int pad = (dsum + 7) & ~7;
        int x = pad;                       // inclusive scan across 64 lanes
        for (int off = 1; off < 64; off <<= 1) {
            int y = __shfl_up(x, off);
            if (t >= off) x += y;
        }
        int nb = gbase + (x - pad);        // node base (exclusive prefix)
        int n0 = b * BRANGE + t;
        if (n0 < Nn) { offsets[n0] = nb; deg[n0] = dsum; }
        for (int i = dsum; i < pad; ++i)
            data[nb + i] = (int)0xF0000000u;   // sentinel: rel 15, src 0
        int q = nb;
#pragma unroll
        for (int r = 0; r < RNUM; ++r) { int c = hist[t * RNUM + r]; hist[t * RNUM + r] = q; q += c; }
    }
    __syncthreads();

    // scatter in place (reads are fully staged in LDS)
    for (int i = t; i < cnt; i += 256) {
        int rec = recs[i];
        int n = (rec >> 16) & (BRANGE - 1);
        int r = (rec >> 22) & 7;
        int pos = atomicAdd(&hist[n * RNUM + r], 1);
        data[pos] = (rec & 0xFFFF) | (r << 28);
    }
}

// ---------- zgemm: Z[n][c] = xb[n] @ Wcol[c], K=128, flattened blocks ----------
// grid (18 chunks, 782 strips); block = 256 thr = 4 waves x 16 nodes; 64 cols.
// Swapped operands: A-frag = W rows (c dim, from 16KB swizzled LDS), B-frag = xb regs.
__global__ __launch_bounds__(256) void zgemm_kernel(
        const unsigned short* __restrict__ xb,    // [npad][128]
        const unsigned short* __restrict__ Wcol,  // [1152][128]
        unsigned short* __restrict__ Z) {         // [npad][1152]
    __shared__ unsigned short Ws[ZCH * 128];      // 16384 B

    const int tid  = threadIdx.x;
    const int lane = tid & 63;
    const int w    = tid >> 6;       // 0..3
    const int l16  = lane & 15;
    const int q    = lane >> 4;      // 0..3
    const int c0   = blockIdx.x * ZCH;
    const int n    = blockIdx.y * ZNB + w * 16 + l16;   // this lane's node

    // xb B-frags: K=128 = 4 windows of 32, loaded ONCE (overlap with staging)
    short8 xq[4];
#pragma unroll
    for (int kw = 0; kw < 4; ++kw)
        xq[kw] = *(const short8*)(xb + (size_t)n * D + kw * 32 + q * 8);

    // stage W chunk: 1024 16B pieces; LDS slot s holds source piece (s&15)^(c&15), c=s>>4
#pragma unroll
    for (int i = 0; i < 4; ++i) {
        int s = i * 256 + w * 64 + lane;
        int c = s >> 4;
        int p = (s & 15) ^ (c & 15);
        gl_lds16(Wcol + (size_t)(c0 + c) * D + p * 8,
                 &Ws[(size_t)(i * 256 + w * 64) * 8]);
    }
    __syncthreads();     // drains vmcnt (xq + stage); the only barrier

    float4v acc[4] = {};
#pragma unroll
    for (int cg = 0; cg < 4; ++cg) {
#pragma unroll
        for (int kw = 0; kw < 4; ++kw) {
            // A-frag: row c = cg*16+l16 (c&15 == l16), logical piece kw*4+q
            short8 a = *(const short8*)(
                &Ws[(((cg * 16 + l16) << 4) + ((kw * 4 + q) ^ l16)) * 8]);
            acc[cg] = __builtin_amdgcn_mfma_f32_16x16x32_bf16(
                a, xq[kw], acc[cg], 0, 0, 0);
        }
    }
    // store: lane holds node n, cols c0 + cg*16 + q*4 .. +3 (4 consecutive bf16)
#pragma unroll
    for (int cg = 0; cg < 4; ++cg) {
        unsigned int lo = f2b(acc[cg][0]) | (f2b(acc[cg][1]) << 16);
        unsigned int hi = f2b(acc[cg][2]) | (f2b(acc[cg][3]) << 16);
        *(uint2*)(Z + (size_t)n * KTOT + c0 + cg * 16 + q * 4) = make_uint2(lo, hi);
    }
}

// ---------- gather: one wave per node; racc += Z[src,rel] rows; direct out ----------
__global__ __launch_bounds__(256) void gather_kernel(
        const unsigned short* __restrict__ Z,     // [npad][1152]
        const int* __restrict__ offsets,          // node base, multiple of 8
        const int* __restrict__ deg,              // real in-degree
        const int* __restrict__ sorted,           // src | rel<<28, sentinel-padded
        const float* __restrict__ bias,
        float* __restrict__ out,
        int Nn) {
    int node = blockIdx.x * 4 + (threadIdx.x >> 6);
    if (node >= Nn) return;
    int lane = threadIdx.x & 63;
    int laneoff = lane * 2;   // bf16-element offset within a 128-wide row

    int b0 = __builtin_amdgcn_readfirstlane(offsets[node]);
    int dg = __builtin_amdgcn_readfirstlane(deg[node]);
    float inv = 1.0f / fmaxf((float)dg, 1.0f);
    int bulk = dg & ~7;
    int rem  = dg & 7;

    float2v racc = {0.0f, 0.0f};

    // full batches: no sentinels, unconditional adds
    for (int e = b0; e < b0 + bulk; e += 8) {
        int pv[8];
#pragma unroll
        for (int j = 0; j < 8; ++j)
            pv[j] = __builtin_amdgcn_readfirstlane(sorted[e + j]);   // SGPR
        unsigned int u[8];
#pragma unroll
        for (int j = 0; j < 8; ++j) {
            int src = pv[j] & 0xFFFF;
            int rel = (((unsigned)pv[j]) >> 28) & 7;
            u[j] = *(const unsigned int*)(Z + (size_t)src * KTOT + rel * D + laneoff);
        }
#pragma unroll
        for (int j = 0; j < 8; ++j) {
            racc.x += b2f_lo(u[j]);
            racc.y += b2f_hi(u[j]);
        }
    }
    // tail batch: rem real edges + sentinels (guarded by j < rem, uniform)
    if (rem) {
        int e = b0 + bulk;
        int pv[8];
#pragma unroll
        for (int j = 0; j < 8; ++j)
            pv[j] = __builtin_amdgcn_readfirstlane(sorted[e + j]);
        unsigned int u[8];
#pragma unroll
        for (int j = 0; j < 8; ++j) {
            int src = pv[j] & 0xFFFF;
            int rel = (((unsigned)pv[j]) >> 28) & 7;
            u[j] = *(const unsigned int*)(Z + (size_t)src * KTOT + rel * D + laneoff);
        }
#pragma unroll
        for (int j = 0; j < 8; ++j) {
            if (j < rem) {
                racc.x += b2f_lo(u[j]);
                racc.y += b2f_hi(u[j]);
            }
        }
    }

    // epilogue: out = relu(Z_self + bias + racc/deg)
    unsigned int zs = *(const unsigned int*)(Z + (size_t)node * KTOT + KREL + laneoff);
    float bx = bias[laneoff];
    float by = bias[laneoff + 1];
    float o0 = fmaxf(b2f_lo(zs) + bx + racc.x * inv, 0.0f);
    float o1 = fmaxf(b2f_hi(zs) + by + racc.y * inv, 0.0f);
    *(float2*)(out + (size_t)node * D + laneoff) = make_float2(o0, o1);
}

extern "C" void kernel_launch(void* const* d_in, const int* in_sizes, int n_in,
                              void* d_out, int out_size, void* d_ws, size_t ws_size,
                              hipStream_t stream) {
    const float* x      = (const float*)d_in[0];
    const float* W_rel  = (const float*)d_in[1];
    const float* W_self = (const float*)d_in[2];
    const float* W_bias = (const float*)d_in[3];
    const int*   ei     = (const int*)d_in[4];
    const int*   et     = (const int*)d_in[5];

    const int Nn = in_sizes[0] / D;       // 50000
    const int E  = in_sizes[4] / 2;       // 800000
    const int npad = ((Nn + ZNB - 1) / ZNB) * ZNB;        // 50048
    const int nbkt = (Nn + BRANGE - 1) >> BSHIFT;         // 782
    const int gz   = nbkt * CSTRIDE;

    // ---- workspace layout (256B aligned chunks) ----
    char* p = (char*)d_ws;
    auto take = [&](size_t bytes) { char* q = p; p += (bytes + 255) & ~(size_t)255; return q; };
    unsigned short* Z    = (unsigned short*)take((size_t)npad * KTOT * sizeof(unsigned short));
    unsigned short* xb   = (unsigned short*)take((size_t)npad * D * sizeof(unsigned short));
    unsigned short* Wcol = (unsigned short*)take((size_t)KTOT * D * sizeof(unsigned short));
    int* offsets = (int*)take((size_t)Nn * sizeof(int));
    int* deg     = (int*)take((size_t)Nn * sizeof(int));
    int* gcur    = (int*)take((size_t)gz * sizeof(int));
    int* data    = (int*)take((size_t)nbkt * BCAP * sizeof(int));  // bucket records -> sorted

    const int xb_blocks = (Nn * 32 + 255) / 256;
    const int wc_blocks = (KTOT * D + 255) / 256;
    const int gz_blocks = (gz + 255) / 256;
    prep_kernel<<<xb_blocks + wc_blocks + gz_blocks, 256, 0, stream>>>(
        x, W_rel, W_self, xb, Wcol, gcur, Nn, xb_blocks, wc_blocks, gz);
    coarse_kernel<<<(E + 2047) / 2048, 256, 0, stream>>>(ei, et, gcur, data, E, nbkt);
    fine_kernel<<<nbkt, 256, 0, stream>>>(data, gcur, offsets, deg, Nn);
    dim3 zgrid(KTOT / ZCH, npad / ZNB);   // (18, 782)
    zgemm_kernel<<<zgrid, 256, 0, stream>>>(xb, Wcol, Z);
    gather_kernel<<<(Nn + 3) / 4, 256, 0, stream>>>(Z, offsets, deg, data, W_bias,
                                                    (float*)d_out, Nn);
}

// Round 10
// 199.290 us; speedup vs baseline: 1.3704x; 1.0611x over previous
//
#include <hip/hip_runtime.h>
#include <hip/hip_bf16.h>

// RGCN layer: out = relu(x @ W_self^T + b + agg/deg)
// Pipeline v20 (5 dispatches): v19 + full-line Z stores in zgemm (RFO elimination)
//   Z[n, 0..1151] = xb[n] @ [W_0|...|W_7|W_self];  out = relu(Zself + b + avg(Z[src,rel]))
//   1. prep: xb = bf16(x), Wcol = bf16 col-major weights [1152][128], zero cursors
//   2. coarse: edges -> 782 buckets of 64 dst-nodes; 4B packed records
//   3. fine: one block per bucket; LDS hist/scan/scatter -> (dst,rel)-sorted + x8 pad
//   4. zgemm: grid (18 col-chunks x 782 node-strips); 64 nodes x 64 cols/block;
//      16KB LDS W-chunk (XOR piece-swizzle), MFMA, then acc -> 9KB LDS transpose ->
//      FULL-LINE stores (4 lanes cover one 64B line per instruction; no partial lines)
//   5. gather: one wave per node; 8-batched scalar edge stream, racc += Z row,
//      epilogue out = relu(Zself + bias + racc*inv) direct.

#define D 128
#define RNUM 8
#define KREL (RNUM * D)      // 1024
#define KTOT (KREL + D)      // 1152 — Z row pitch
#define ZCH 64               // zgemm cols per block
#define ZNB 64               // zgemm nodes per block (4 waves x 16)
#define ZSP 72               // Zs LDS pitch in elems (16B-aligned rows, bank spread)

#define BSHIFT 6             // 64 nodes per bucket
#define BRANGE 64
#define BCAP   2048          // slots per bucket region (avg fill ~1250)
#define NBKT_MAX 784
#define CSTRIDE 16           // bucket cursor padding (ints) to spread atomic lines

typedef short short8 __attribute__((ext_vector_type(8)));
typedef float float4v __attribute__((ext_vector_type(4)));
typedef float float2v __attribute__((ext_vector_type(2)));

// fp32 -> bf16 round-nearest-even (bit pattern)
static __device__ __forceinline__ unsigned int f2b(float f) {
    unsigned int u = __float_as_uint(f);
    return (u + 0x7fffu + ((u >> 16) & 1u)) >> 16;
}
static __device__ __forceinline__ float b2f_lo(unsigned int u) {
    return __uint_as_float(u << 16);
}
static __device__ __forceinline__ float b2f_hi(unsigned int u) {
    return __uint_as_float(u & 0xffff0000u);
}

static __device__ __forceinline__ void gl_lds16(const void* g, void* l) {
    __builtin_amdgcn_global_load_lds(
        (const __attribute__((address_space(1))) unsigned int*)g,
        (__attribute__((address_space(3))) unsigned int*)l, 16, 0, 0);
}

// ---------- prep (3 block ranges): xb | Wcol | zero bucket cursors ----------
__global__ void prep_kernel(const float* __restrict__ x,
                            const float* __restrict__ W_rel,
                            const float* __restrict__ W_self,
                            unsigned short* __restrict__ xb,
                            unsigned short* __restrict__ Wcol,
                            int* __restrict__ gcur,
                            int Nn, int xb_blocks, int wc_blocks, int gz) {
    if (blockIdx.x < (unsigned)xb_blocks) {
        int t = blockIdx.x * 256 + threadIdx.x;
        int n = t >> 5;              // 32 threads/row, 4 cols each
        int c = (t & 31) * 4;
        if (n >= Nn) return;
        float4 v = *(const float4*)(x + (size_t)n * D + c);
        unsigned int p0 = f2b(v.x) | (f2b(v.y) << 16);
        unsigned int p1 = f2b(v.z) | (f2b(v.w) << 16);
        *(uint2*)(xb + (size_t)n * D + c) = make_uint2(p0, p1);
    } else if (blockIdx.x < (unsigned)(xb_blocks + wc_blocks)) {
        int idx = (blockIdx.x - xb_blocks) * 256 + threadIdx.x;
        if (idx >= KTOT * D) return;
        int c = idx >> 7;            // output col 0..1151
        int k = idx & 127;           // input dim
        float v = (c < KREL)
            ? W_rel[(size_t)((c >> 7) * D + k) * D + (c & 127)]   // W_rel[r][k][o]
            : W_self[(size_t)(c - KREL) * D + k];                 // W_self[o][k]
        Wcol[idx] = (unsigned short)f2b(v);
    } else {
        int idx = (blockIdx.x - xb_blocks - wc_blocks) * 256 + threadIdx.x;
        if (idx < gz) gcur[idx] = 0;
    }
}

// ---------- coarse: edges -> buckets, block-aggregated reservation ----------
__global__ __launch_bounds__(256) void coarse_kernel(
        const int* __restrict__ ei, const int* __restrict__ et,
        int* __restrict__ gcur, int* __restrict__ data, int E, int nbkt) {
    __shared__ int cnt[NBKT_MAX];
    int t = threadIdx.x;
    for (int i = t; i < nbkt; i += 256) cnt[i] = 0;
    __syncthreads();

    int rec[8], rb[8], rk[8];
    int e0 = blockIdx.x * 2048;
#pragma unroll
    for (int j = 0; j < 8; ++j) {
        int e = e0 + j * 256 + t;
        bool ok = e < E;
        int s = ok ? ei[e] : 0;
        int d = ok ? ei[E + e] : 0;
        int r = ok ? et[e] : 0;
        int bkt = d >> BSHIFT;
        rec[j] = s | ((d & (BRANGE - 1)) << 16) | (r << 22);
        rb[j] = ok ? bkt : -1;
        rk[j] = ok ? atomicAdd(&cnt[bkt], 1) : 0;
    }
    __syncthreads();

    // reserve global space per nonempty bucket; store absolute write base in cnt[]
    for (int i = t; i < nbkt; i += 256) {
        int c = cnt[i];
        if (c) cnt[i] = i * BCAP + atomicAdd(&gcur[i * CSTRIDE], c);
    }
    __syncthreads();

#pragma unroll
    for (int j = 0; j < 8; ++j) {
        if (rb[j] >= 0) {
            int pos = cnt[rb[j]] + rk[j];
            if (pos < (rb[j] + 1) * BCAP)   // capacity guard (never hit on sane data)
                data[pos] = rec[j];
        }
    }
}

// ---------- fine: one block per bucket; LDS hist + scan + in-place scatter ----------
__global__ __launch_bounds__(256) void fine_kernel(
        int* __restrict__ data, const int* __restrict__ gcur,
        int* __restrict__ offsets, int* __restrict__ deg, int Nn) {
    __shared__ int recs[BCAP];            // 8 KB
    __shared__ int hist[BRANGE * RNUM];   // 2 KB: counts, then converted to cursors
    int b = blockIdx.x;
    int t = threadIdx.x;
    int gbase = b * BCAP;
    int cnt = gcur[b * CSTRIDE];
    if (cnt > BCAP) cnt = BCAP;

    for (int i = t; i < BRANGE * RNUM; i += 256) hist[i] = 0;
    __syncthreads();

    // stage records to LDS + per-(node,rel) histogram (LDS atomics)
    for (int i = t; i < cnt; i += 256) {
        int rec = data[gbase + i];
        recs[i] = rec;
        int n = (rec >> 16) & (BRANGE - 1);
        int r = (rec >> 22) & 7;
        atomicAdd(&hist[n * RNUM + r], 1);
    }
    __syncthreads();

    // first wave: per-node padded scan, emit offsets/deg, sentinels, rel cursors
    if (t < BRANGE) {
        int dsum = 0;
#pragma unroll
        for (int r = 0; r < RNUM; ++r) dsum += hist[t * RNUM + r];
        int pad = (dsum + 7) & ~7;
        int x = pad;                       // inclusive scan across 64 lanes
        for (int off = 1; off < 64; off <<= 1) {
            int y = __shfl_up(x, off);
            if (t >= off) x += y;
        }
        int nb = gbase + (x - pad);        // node base (exclusive prefix)
        int n0 = b * BRANGE + t;
        if (n0 < Nn) { offsets[n0] = nb; deg[n0] = dsum; }
        for (int i = dsum; i < pad; ++i)
            data[nb + i] = (int)0xF0000000u;   // sentinel: rel 15, src 0
        int q = nb;
#pragma unroll
        for (int r = 0; r < RNUM; ++r) { int c = hist[t * RNUM + r]; hist[t * RNUM + r] = q; q += c; }
    }
    __syncthreads();

    // scatter in place (reads are fully staged in LDS)
    for (int i = t; i < cnt; i += 256) {
        int rec = recs[i];
        int n = (rec >> 16) & (BRANGE - 1);
        int r = (rec >> 22) & 7;
        int pos = atomicAdd(&hist[n * RNUM + r], 1);
        data[pos] = (rec & 0xFFFF) | (r << 28);
    }
}

// ---------- zgemm: Z[n][c] = xb[n] @ Wcol[c], K=128, full-line stores ----------
// grid (18 chunks, 782 strips); block = 256 thr = 4 waves x 16 nodes; 64 cols.
// Swapped operands: A-frag = W rows (c dim, from 16KB swizzled LDS), B-frag = xb regs.
// Epilogue: acc -> Zs LDS transpose -> 4 lanes cover one full 64B line per store.
__global__ __launch_bounds__(256) void zgemm_kernel(
        const unsigned short* __restrict__ xb,    // [npad][128]
        const unsigned short* __restrict__ Wcol,  // [1152][128]
        unsigned short* __restrict__ Z) {         // [npad][1152]
    __shared__ unsigned short Ws[ZCH * 128];      // 16384 B
    __shared__ unsigned short Zs[ZNB * ZSP];      // 9216 B

    const int tid  = threadIdx.x;
    const int lane = tid & 63;
    const int w    = tid >> 6;       // 0..3
    const int l16  = lane & 15;
    const int q    = lane >> 4;      // 0..3
    const int c0   = blockIdx.x * ZCH;
    const int n0   = blockIdx.y * ZNB;
    const int n    = n0 + w * 16 + l16;    // this lane's node

    // xb B-frags: K=128 = 4 windows of 32, loaded ONCE (overlap with staging)
    short8 xq[4];
#pragma unroll
    for (int kw = 0; kw < 4; ++kw)
        xq[kw] = *(const short8*)(xb + (size_t)n * D + kw * 32 + q * 8);

    // stage W chunk: 1024 16B pieces; LDS slot s holds source piece (s&15)^(c&15), c=s>>4
#pragma unroll
    for (int i = 0; i < 4; ++i) {
        int s = i * 256 + w * 64 + lane;
        int c = s >> 4;
        int p = (s & 15) ^ (c & 15);
        gl_lds16(Wcol + (size_t)(c0 + c) * D + p * 8,
                 &Ws[(size_t)(i * 256 + w * 64) * 8]);
    }
    __syncthreads();     // drains vmcnt (xq + stage)

    float4v acc[4] = {};
#pragma unroll
    for (int cg = 0; cg < 4; ++cg) {
#pragma unroll
        for (int kw = 0; kw < 4; ++kw) {
            // A-frag: row c = cg*16+l16 (c&15 == l16), logical piece kw*4+q
            short8 a = *(const short8*)(
                &Ws[(((cg * 16 + l16) << 4) + ((kw * 4 + q) ^ l16)) * 8]);
            acc[cg] = __builtin_amdgcn_mfma_f32_16x16x32_bf16(
                a, xq[kw], acc[cg], 0, 0, 0);
        }
    }

    // park accs in LDS: node row = w*16+l16, col = cg*16 + q*4 (8B per write)
#pragma unroll
    for (int cg = 0; cg < 4; ++cg) {
        unsigned int lo = f2b(acc[cg][0]) | (f2b(acc[cg][1]) << 16);
        unsigned int hi = f2b(acc[cg][2]) | (f2b(acc[cg][3]) << 16);
        *(uint2*)(&Zs[(w * 16 + l16) * ZSP + cg * 16 + q * 4]) = make_uint2(lo, hi);
    }
    __syncthreads();

    // full-line stores: thread t -> node row t>>2, 16B piece t&3 (+64B for 2nd half).
    // Store instr 1: lanes 4k..4k+3 cover one whole 64B line of row k. Same instr 2.
    {
        int row = tid >> 2;
        int pc  = (tid & 3) * 8;     // elem offset 0,8,16,24
        short8 z0 = *(const short8*)(&Zs[row * ZSP + pc]);
        short8 z1 = *(const short8*)(&Zs[row * ZSP + pc + 32]);
        unsigned short* dst = Z + (size_t)(n0 + row) * KTOT + c0;
        *(short8*)(dst + pc)      = z0;
        *(short8*)(dst + pc + 32) = z1;
    }
}

// ---------- gather: one wave per node; racc += Z[src,rel] rows; direct out ----------
__global__ __launch_bounds__(256) void gather_kernel(
        const unsigned short* __restrict__ Z,     // [npad][1152]
        const int* __restrict__ offsets,          // node base, multiple of 8
        const int* __restrict__ deg,              // real in-degree
        const int* __restrict__ sorted,           // src | rel<<28, sentinel-padded
        const float* __restrict__ bias,
        float* __restrict__ out,
        int Nn) {
    int node = blockIdx.x * 4 + (threadIdx.x >> 6);
    if (node >= Nn) return;
    int lane = threadIdx.x & 63;
    int laneoff = lane * 2;   // bf16-element offset within a 128-wide row

    int b0 = __builtin_amdgcn_readfirstlane(offsets[node]);
    int dg = __builtin_amdgcn_readfirstlane(deg[node]);
    float inv = 1.0f / fmaxf((float)dg, 1.0f);
    int bulk = dg & ~7;
    int rem  = dg & 7;

    float2v racc = {0.0f, 0.0f};

    // full batches: no sentinels, unconditional adds
    for (int e = b0; e < b0 + bulk; e += 8) {
        int pv[8];
#pragma unroll
        for (int j = 0; j < 8; ++j)
            pv[j] = __builtin_amdgcn_readfirstlane(sorted[e + j]);   // SGPR
        unsigned int u[8];
#pragma unroll
        for (int j = 0; j < 8; ++j) {
            int src = pv[j] & 0xFFFF;
            int rel = (((unsigned)pv[j]) >> 28) & 7;
            u[j] = *(const unsigned int*)(Z + (size_t)src * KTOT + rel * D + laneoff);
        }
#pragma unroll
        for (int j = 0; j < 8; ++j) {
            racc.x += b2f_lo(u[j]);
            racc.y += b2f_hi(u[j]);
        }
    }
    // tail batch: rem real edges + sentinels (guarded by j < rem, uniform)
    if (rem) {
        int e = b0 + bulk;
        int pv[8];
#pragma unroll
        for (int j = 0; j < 8; ++j)
            pv[j] = __builtin_amdgcn_readfirstlane(sorted[e + j]);
        unsigned int u[8];
#pragma unroll
        for (int j = 0; j < 8; ++j) {
            int src = pv[j] & 0xFFFF;
            int rel = (((unsigned)pv[j]) >> 28) & 7;
            u[j] = *(const unsigned int*)(Z + (size_t)src * KTOT + rel * D + laneoff);
        }
#pragma unroll
        for (int j = 0; j < 8; ++j) {
            if (j < rem) {
                racc.x += b2f_lo(u[j]);
                racc.y += b2f_hi(u[j]);
            }
        }
    }

    // epilogue: out = relu(Z_self + bias + racc/deg)
    unsigned int zs = *(const unsigned int*)(Z + (size_t)node * KTOT + KREL + laneoff);
    float bx = bias[laneoff];
    float by = bias[laneoff + 1];
    float o0 = fmaxf(b2f_lo(zs) + bx + racc.x * inv, 0.0f);
    float o1 = fmaxf(b2f_hi(zs) + by + racc.y * inv, 0.0f);
    *(float2*)(out + (size_t)node * D + laneoff) = make_float2(o0, o1);
}

extern "C" void kernel_launch(void* const* d_in, const int* in_sizes, int n_in,
                              void* d_out, int out_size, void* d_ws, size_t ws_size,
                              hipStream_t stream) {
    const float* x      = (const float*)d_in[0];
    const float* W_rel  = (const float*)d_in[1];
    const float* W_self = (const float*)d_in[2];
    const float* W_bias = (const float*)d_in[3];
    const int*   ei     = (const int*)d_in[4];
    const int*   et     = (const int*)d_in[5];

    const int Nn = in_sizes[0] / D;       // 50000
    const int E  = in_sizes[4] / 2;       // 800000
    const int npad = ((Nn + ZNB - 1) / ZNB) * ZNB;        // 50048
    const int nbkt = (Nn + BRANGE - 1) >> BSHIFT;         // 782
    const int gz   = nbkt * CSTRIDE;

    // ---- workspace layout (256B aligned chunks) ----
    char* p = (char*)d_ws;
    auto take = [&](size_t bytes) { char* q = p; p += (bytes + 255) & ~(size_t)255; return q; };
    unsigned short* Z    = (unsigned short*)take((size_t)npad * KTOT * sizeof(unsigned short));
    unsigned short* xb   = (unsigned short*)take((size_t)npad * D * sizeof(unsigned short));
    unsigned short* Wcol = (unsigned short*)take((size_t)KTOT * D * sizeof(unsigned short));
    int* offsets = (int*)take((size_t)Nn * sizeof(int));
    int* deg     = (int*)take((size_t)Nn * sizeof(int));
    int* gcur    = (int*)take((size_t)gz * sizeof(int));
    int* data    = (int*)take((size_t)nbkt * BCAP * sizeof(int));  // bucket records -> sorted

    const int xb_blocks = (Nn * 32 + 255) / 256;
    const int wc_blocks = (KTOT * D + 255) / 256;
    const int gz_blocks = (gz + 255) / 256;
    prep_kernel<<<xb_blocks + wc_blocks + gz_blocks, 256, 0, stream>>>(
        x, W_rel, W_self, xb, Wcol, gcur, Nn, xb_blocks, wc_blocks, gz);
    coarse_kernel<<<(E + 2047) / 2048, 256, 0, stream>>>(ei, et, gcur, data, E, nbkt);
    fine_kernel<<<nbkt, 256, 0, stream>>>(data, gcur, offsets, deg, Nn);
    dim3 zgrid(KTOT / ZCH, npad / ZNB);   // (18, 782)
    zgemm_kernel<<<zgrid, 256, 0, stream>>>(xb, Wcol, Z);
    gather_kernel<<<(Nn + 3) / 4, 256, 0, stream>>>(Z, offsets, deg, data, W_bias,
                                                    (float*)d_out, Nn);
}

// Round 11
// 194.627 us; speedup vs baseline: 1.4033x; 1.0240x over previous
//
#include <hip/hip_runtime.h>
#include <hip/hip_bf16.h>

// RGCN layer: out = relu(x @ W_self^T + b + agg/deg)
// Pipeline v21 (3 dispatches + memset): v20 merged + XCD-contiguous zgemm
//   Z[n, 0..1151] = xb[n] @ [W_0|...|W_7|W_self];  out = relu(Zself + b + avg(Z[src,rel]))
//   0. hipMemsetAsync: zero bucket cursors
//   1. K1 prep+coarse (independent ranges): xb = bf16(x) | Wcol | coarse bucket sort
//   2. K2 zgemm+fine (independent ranges, LDS union):
//      zgemm: XCD-contiguous (strip,chunk) decode — all 18 chunks of a strip and 98
//             consecutive strips on one XCD -> xb fetched into exactly one L2;
//             16KB LDS W-chunk (XOR piece-swizzle), MFMA, Zs transpose, full-line stores
//      fine:  one block per bucket; LDS hist/scan/scatter -> (dst,rel)-sorted + x8 pad
//   3. K3 gather: one wave per node; 8-batched scalar edge stream, racc += Z row,
//      epilogue out = relu(Zself + bias + racc*inv) direct.

#define D 128
#define RNUM 8
#define KREL (RNUM * D)      // 1024
#define KTOT (KREL + D)      // 1152 — Z row pitch
#define ZCH 64               // zgemm cols per block
#define ZNB 64               // zgemm nodes per block (4 waves x 16)
#define ZSP 72               // Zs LDS pitch in elems

#define BSHIFT 6             // 64 nodes per bucket
#define BRANGE 64
#define BCAP   2048          // slots per bucket region (avg fill ~1250)
#define NBKT_MAX 784
#define CSTRIDE 16           // bucket cursor padding (ints) to spread atomic lines

typedef short short8 __attribute__((ext_vector_type(8)));
typedef float float4v __attribute__((ext_vector_type(4)));
typedef float float2v __attribute__((ext_vector_type(2)));

// fp32 -> bf16 round-nearest-even (bit pattern)
static __device__ __forceinline__ unsigned int f2b(float f) {
    unsigned int u = __float_as_uint(f);
    return (u + 0x7fffu + ((u >> 16) & 1u)) >> 16;
}
static __device__ __forceinline__ float b2f_lo(unsigned int u) {
    return __uint_as_float(u << 16);
}
static __device__ __forceinline__ float b2f_hi(unsigned int u) {
    return __uint_as_float(u & 0xffff0000u);
}

static __device__ __forceinline__ void gl_lds16(const void* g, void* l) {
    __builtin_amdgcn_global_load_lds(
        (const __attribute__((address_space(1))) unsigned int*)g,
        (__attribute__((address_space(3))) unsigned int*)l, 16, 0, 0);
}

// ---------- K1: prep (xb | Wcol) + coarse bucket sort (independent ranges) ----------
__global__ __launch_bounds__(256) void prep_coarse_kernel(
        const float* __restrict__ x,
        const float* __restrict__ W_rel,
        const float* __restrict__ W_self,
        const int* __restrict__ ei, const int* __restrict__ et,
        unsigned short* __restrict__ xb,
        unsigned short* __restrict__ Wcol,
        int* __restrict__ gcur, int* __restrict__ data,
        int Nn, int E, int xb_blocks, int wc_blocks, int nbkt) {
    __shared__ int cnt[NBKT_MAX];
    if (blockIdx.x < (unsigned)xb_blocks) {
        int t = blockIdx.x * 256 + threadIdx.x;
        int n = t >> 5;              // 32 threads/row, 4 cols each
        int c = (t & 31) * 4;
        if (n >= Nn) return;
        float4 v = *(const float4*)(x + (size_t)n * D + c);
        unsigned int p0 = f2b(v.x) | (f2b(v.y) << 16);
        unsigned int p1 = f2b(v.z) | (f2b(v.w) << 16);
        *(uint2*)(xb + (size_t)n * D + c) = make_uint2(p0, p1);
    } else if (blockIdx.x < (unsigned)(xb_blocks + wc_blocks)) {
        int idx = (blockIdx.x - xb_blocks) * 256 + threadIdx.x;
        if (idx >= KTOT * D) return;
        int c = idx >> 7;            // output col 0..1151
        int k = idx & 127;           // input dim
        float v = (c < KREL)
            ? W_rel[(size_t)((c >> 7) * D + k) * D + (c & 127)]   // W_rel[r][k][o]
            : W_self[(size_t)(c - KREL) * D + k];                 // W_self[o][k]
        Wcol[idx] = (unsigned short)f2b(v);
    } else {
        // ---- coarse: edges -> buckets, block-aggregated reservation ----
        int blk = blockIdx.x - xb_blocks - wc_blocks;
        int t = threadIdx.x;
        for (int i = t; i < nbkt; i += 256) cnt[i] = 0;
        __syncthreads();

        int rec[8], rb[8], rk[8];
        int e0 = blk * 2048;
#pragma unroll
        for (int j = 0; j < 8; ++j) {
            int e = e0 + j * 256 + t;
            bool ok = e < E;
            int s = ok ? ei[e] : 0;
            int d = ok ? ei[E + e] : 0;
            int r = ok ? et[e] : 0;
            int bkt = d >> BSHIFT;
            rec[j] = s | ((d & (BRANGE - 1)) << 16) | (r << 22);
            rb[j] = ok ? bkt : -1;
            rk[j] = ok ? atomicAdd(&cnt[bkt], 1) : 0;
        }
        __syncthreads();

        // reserve global space per nonempty bucket; store absolute write base
        for (int i = t; i < nbkt; i += 256) {
            int c = cnt[i];
            if (c) cnt[i] = i * BCAP + atomicAdd(&gcur[i * CSTRIDE], c);
        }
        __syncthreads();

#pragma unroll
        for (int j = 0; j < 8; ++j) {
            if (rb[j] >= 0) {
                int pos = cnt[rb[j]] + rk[j];
                if (pos < (rb[j] + 1) * BCAP)   // capacity guard
                    data[pos] = rec[j];
            }
        }
    }
}

// ---------- K2: zgemm (XCD-contiguous) + fine (independent ranges; LDS union) ----------
// zgemm range first (blockIdx 0..ZG-1) so bid%8 == XCD residue alignment holds.
__global__ __launch_bounds__(256) void zgemm_fine_kernel(
        const unsigned short* __restrict__ xb,    // [npad][128]
        const unsigned short* __restrict__ Wcol,  // [1152][128]
        unsigned short* __restrict__ Z,           // [npad][1152]
        int* __restrict__ data, const int* __restrict__ gcur,
        int* __restrict__ offsets, int* __restrict__ deg,
        int Nn, int nstrip, int spx, int zg) {
    __shared__ __align__(16) char smem[25600];    // union: zgemm 25600 | fine 10240

    if ((int)blockIdx.x < zg) {
        // ======== zgemm: 64 nodes x 64 cols; XCD-contiguous strip mapping ========
        unsigned short* Ws = (unsigned short*)smem;            // 16384 B
        unsigned short* Zs = (unsigned short*)(smem + 16384);  //  9216 B

        const int xcd = blockIdx.x & 7;
        const int i0  = blockIdx.x >> 3;
        const int strip = xcd * spx + i0 / 18;
        const int chunk = i0 % 18;
        if (strip >= nstrip) return;               // pad strips (uniform)

        const int tid  = threadIdx.x;
        const int lane = tid & 63;
        const int w    = tid >> 6;       // 0..3
        const int l16  = lane & 15;
        const int q    = lane >> 4;      // 0..3
        const int c0   = chunk * ZCH;
        const int n0   = strip * ZNB;
        const int n    = n0 + w * 16 + l16;    // this lane's node

        // xb B-frags: K=128 = 4 windows of 32, loaded ONCE
        short8 xq[4];
#pragma unroll
        for (int kw = 0; kw < 4; ++kw)
            xq[kw] = *(const short8*)(xb + (size_t)n * D + kw * 32 + q * 8);

        // stage W chunk: 1024 16B pieces; LDS slot s holds piece (s&15)^(c&15)
#pragma unroll
        for (int i = 0; i < 4; ++i) {
            int s = i * 256 + w * 64 + lane;
            int c = s >> 4;
            int p = (s & 15) ^ (c & 15);
            gl_lds16(Wcol + (size_t)(c0 + c) * D + p * 8,
                     &Ws[(size_t)(i * 256 + w * 64) * 8]);
        }
        __syncthreads();     // drains vmcnt (xq + stage)

        float4v acc[4] = {};
#pragma unroll
        for (int cg = 0; cg < 4; ++cg) {
#pragma unroll
            for (int kw = 0; kw < 4; ++kw) {
                // A-frag: row c = cg*16+l16 (c&15 == l16), logical piece kw*4+q
                short8 a = *(const short8*)(
                    &Ws[(((cg * 16 + l16) << 4) + ((kw * 4 + q) ^ l16)) * 8]);
                acc[cg] = __builtin_amdgcn_mfma_f32_16x16x32_bf16(
                    a, xq[kw], acc[cg], 0, 0, 0);
            }
        }

        // park accs in LDS (node row = w*16+l16, col = cg*16 + q*4)
#pragma unroll
        for (int cg = 0; cg < 4; ++cg) {
            unsigned int lo = f2b(acc[cg][0]) | (f2b(acc[cg][1]) << 16);
            unsigned int hi = f2b(acc[cg][2]) | (f2b(acc[cg][3]) << 16);
            *(uint2*)(&Zs[(w * 16 + l16) * ZSP + cg * 16 + q * 4]) = make_uint2(lo, hi);
        }
        __syncthreads();

        // full-line stores: thread t -> node row t>>2, 16B piece t&3 (+64B 2nd half)
        {
            int row = tid >> 2;
            int pc  = (tid & 3) * 8;     // elem offset 0,8,16,24
            short8 z0 = *(const short8*)(&Zs[row * ZSP + pc]);
            short8 z1 = *(const short8*)(&Zs[row * ZSP + pc + 32]);
            unsigned short* dst = Z + (size_t)(n0 + row) * KTOT + c0;
            *(short8*)(dst + pc)      = z0;
            *(short8*)(dst + pc + 32) = z1;
        }
    } else {
        // ======== fine: one block per bucket; LDS hist + scan + in-place scatter ==
        int* recs = (int*)smem;               // 8 KB
        int* hist = (int*)(smem + 8192);      // 2 KB
        int b = blockIdx.x - zg;
        int t = threadIdx.x;
        int gbase = b * BCAP;
        int cnt = gcur[b * CSTRIDE];
        if (cnt > BCAP) cnt = BCAP;

        for (int i = t; i < BRANGE * RNUM; i += 256) hist[i] = 0;
        __syncthreads();

        // stage records to LDS + per-(node,rel) histogram (LDS atomics)
        for (int i = t; i < cnt; i += 256) {
            int rec = data[gbase + i];
            recs[i] = rec;
            int n = (rec >> 16) & (BRANGE - 1);
            int r = (rec >> 22) & 7;
            atomicAdd(&hist[n * RNUM + r], 1);
        }
        __syncthreads();

        // first wave: per-node padded scan, emit offsets/deg, sentinels, cursors
        if (t < BRANGE) {
            int dsum = 0;
#pragma unroll
            for (int r = 0; r < RNUM; ++r) dsum += hist[t * RNUM + r];
            int pad = (dsum + 7) & ~7;
            int x = pad;                       // inclusive scan across 64 lanes
            for (int off = 1; off < 64; off <<= 1) {
                int y = __shfl_up(x, off);
                if (t >= off) x += y;
            }
            int nb = gbase + (x - pad);        // node base (exclusive prefix)
            int n0 = b * BRANGE + t;
            if (n0 < Nn) { offsets[n0] = nb; deg[n0] = dsum; }
            for (int i = dsum; i < pad; ++i)
                data[nb + i] = (int)0xF0000000u;   // sentinel: rel 15, src 0
            int q = nb;
#pragma unroll
            for (int r = 0; r < RNUM; ++r) {
                int c = hist[t * RNUM + r]; hist[t * RNUM + r] = q; q += c;
            }
        }
        __syncthreads();

        // scatter in place (reads are fully staged in LDS)
        for (int i = t; i < cnt; i += 256) {
            int rec = recs[i];
            int n = (rec >> 16) & (BRANGE - 1);
            int r = (rec >> 22) & 7;
            int pos = atomicAdd(&hist[n * RNUM + r], 1);
            data[pos] = (rec & 0xFFFF) | (r << 28);
        }
    }
}

// ---------- K3 gather: one wave per node; racc += Z[src,rel] rows; direct out ----------
__global__ __launch_bounds__(256) void gather_kernel(
        const unsigned short* __restrict__ Z,     // [npad][1152]
        const int* __restrict__ offsets,          // node base, multiple of 8
        const int* __restrict__ deg,              // real in-degree
        const int* __restrict__ sorted,           // src | rel<<28, sentinel-padded
        const float* __restrict__ bias,
        float* __restrict__ out,
        int Nn) {
    int node = blockIdx.x * 4 + (threadIdx.x >> 6);
    if (node >= Nn) return;
    int lane = threadIdx.x & 63;
    int laneoff = lane * 2;   // bf16-element offset within a 128-wide row

    int b0 = __builtin_amdgcn_readfirstlane(offsets[node]);
    int dg = __builtin_amdgcn_readfirstlane(deg[node]);
    float inv = 1.0f / fmaxf((float)dg, 1.0f);
    int bulk = dg & ~7;
    int rem  = dg & 7;

    float2v racc = {0.0f, 0.0f};

    // full batches: no sentinels, unconditional adds
    for (int e = b0; e < b0 + bulk; e += 8) {
        int pv[8];
#pragma unroll
        for (int j = 0; j < 8; ++j)
            pv[j] = __builtin_amdgcn_readfirstlane(sorted[e + j]);   // SGPR
        unsigned int u[8];
#pragma unroll
        for (int j = 0; j < 8; ++j) {
            int src = pv[j] & 0xFFFF;
            int rel = (((unsigned)pv[j]) >> 28) & 7;
            u[j] = *(const unsigned int*)(Z + (size_t)src * KTOT + rel * D + laneoff);
        }
#pragma unroll
        for (int j = 0; j < 8; ++j) {
            racc.x += b2f_lo(u[j]);
            racc.y += b2f_hi(u[j]);
        }
    }
    // tail batch: rem real edges + sentinels (guarded by j < rem, uniform)
    if (rem) {
        int e = b0 + bulk;
        int pv[8];
#pragma unroll
        for (int j = 0; j < 8; ++j)
            pv[j] = __builtin_amdgcn_readfirstlane(sorted[e + j]);
        unsigned int u[8];
#pragma unroll
        for (int j = 0; j < 8; ++j) {
            int src = pv[j] & 0xFFFF;
            int rel = (((unsigned)pv[j]) >> 28) & 7;
            u[j] = *(const unsigned int*)(Z + (size_t)src * KTOT + rel * D + laneoff);
        }
#pragma unroll
        for (int j = 0; j < 8; ++j) {
            if (j < rem) {
                racc.x += b2f_lo(u[j]);
                racc.y += b2f_hi(u[j]);
            }
        }
    }

    // epilogue: out = relu(Z_self + bias + racc/deg)
    unsigned int zs = *(const unsigned int*)(Z + (size_t)node * KTOT + KREL + laneoff);
    float bx = bias[laneoff];
    float by = bias[laneoff + 1];
    float o0 = fmaxf(b2f_lo(zs) + bx + racc.x * inv, 0.0f);
    float o1 = fmaxf(b2f_hi(zs) + by + racc.y * inv, 0.0f);
    *(float2*)(out + (size_t)node * D + laneoff) = make_float2(o0, o1);
}

extern "C" void kernel_launch(void* const* d_in, const int* in_sizes, int n_in,
                              void* d_out, int out_size, void* d_ws, size_t ws_size,
                              hipStream_t stream) {
    const float* x      = (const float*)d_in[0];
    const float* W_rel  = (const float*)d_in[1];
    const float* W_self = (const float*)d_in[2];
    const float* W_bias = (const float*)d_in[3];
    const int*   ei     = (const int*)d_in[4];
    const int*   et     = (const int*)d_in[5];

    const int Nn = in_sizes[0] / D;       // 50000
    const int E  = in_sizes[4] / 2;       // 800000
    const int npad = ((Nn + ZNB - 1) / ZNB) * ZNB;        // 50048
    const int nstrip = npad / ZNB;                        // 782
    const int spx  = (nstrip + 7) / 8;                    // 98 strips per XCD
    const int zg   = spx * 8 * 18;                        // 14112 zgemm blocks
    const int nbkt = (Nn + BRANGE - 1) >> BSHIFT;         // 782
    const int gz   = nbkt * CSTRIDE;

    // ---- workspace layout (256B aligned chunks) ----
    char* p = (char*)d_ws;
    auto take = [&](size_t bytes) { char* q = p; p += (bytes + 255) & ~(size_t)255; return q; };
    unsigned short* Z    = (unsigned short*)take((size_t)npad * KTOT * sizeof(unsigned short));
    unsigned short* xb   = (unsigned short*)take((size_t)npad * D * sizeof(unsigned short));
    unsigned short* Wcol = (unsigned short*)take((size_t)KTOT * D * sizeof(unsigned short));
    int* offsets = (int*)take((size_t)Nn * sizeof(int));
    int* deg     = (int*)take((size_t)Nn * sizeof(int));
    int* gcur    = (int*)take((size_t)gz * sizeof(int));
    int* data    = (int*)take((size_t)nbkt * BCAP * sizeof(int));  // bucket records -> sorted

    const int xb_blocks = (Nn * 32 + 255) / 256;
    const int wc_blocks = (KTOT * D + 255) / 256;
    const int co_blocks = (E + 2047) / 2048;

    hipMemsetAsync(gcur, 0, (size_t)gz * sizeof(int), stream);
    prep_coarse_kernel<<<xb_blocks + wc_blocks + co_blocks, 256, 0, stream>>>(
        x, W_rel, W_self, ei, et, xb, Wcol, gcur, data, Nn, E,
        xb_blocks, wc_blocks, nbkt);
    zgemm_fine_kernel<<<zg + nbkt, 256, 0, stream>>>(
        xb, Wcol, Z, data, gcur, offsets, deg, Nn, nstrip, spx, zg);
    gather_kernel<<<(Nn + 3) / 4, 256, 0, stream>>>(Z, offsets, deg, data, W_bias,
                                                    (float*)d_out, Nn);
}

// Round 12
// 186.538 us; speedup vs baseline: 1.4641x; 1.0434x over previous
//
#include <hip/hip_runtime.h>
#include <hip/hip_bf16.h>

// RGCN layer: out = relu(x @ W_self^T + b + agg/deg)
// Pipeline v22 (3 dispatches, no memset): write-contiguous sort + offset records
//   Z[n, 0..1151] = xb[n] @ [W_0|...|W_7|W_self];  out = relu(Zself + b + avg(Z[src,rel]))
//   1. K1 prep+coarse+zrow (block ranges):
//      xb = bf16(x) | Wcol | coarse: LDS presort by bucket -> CONTIGUOUS 8KB record
//      chunk + cmat prefix row per block (no global atomics) | zero sentinel Z-row
//   2. K2 zgemm+fine (ranges, LDS union):
//      zgemm: XCD-contiguous (strip,chunk); 16KB W LDS (XOR swizzle), MFMA,
//             Zs transpose, full-line stores  [unchanged from v21]
//      fine:  per bucket: read 391 runs from chunks (pass A count, pass B scatter)
//             -> sorted[] dst-grouped, x8 pad, records = Z element offsets;
//             sentinels point at zeroed row
//   3. K3 gather: one wave per node; 16-deep unconditional batches (+8 tail),
//      zero decode (records are element offsets), epilogue direct to out.

#define D 128
#define RNUM 8
#define KREL (RNUM * D)      // 1024
#define KTOT (KREL + D)      // 1152 — Z row pitch
#define ZCH 64               // zgemm cols per block
#define ZNB 64               // zgemm nodes per block (4 waves x 16)
#define ZSP 72               // Zs LDS pitch in elems

#define BSHIFT 6             // 64 nodes per bucket
#define BRANGE 64
#define BCAP   2048          // slots per bucket region of sorted[] (avg fill ~1250)
#define CROW   784           // cmat row stride (782 buckets + sentinel, padded)

typedef short short8 __attribute__((ext_vector_type(8)));
typedef float float4v __attribute__((ext_vector_type(4)));

// fp32 -> bf16 round-nearest-even (bit pattern)
static __device__ __forceinline__ unsigned int f2b(float f) {
    unsigned int u = __float_as_uint(f);
    return (u + 0x7fffu + ((u >> 16) & 1u)) >> 16;
}
static __device__ __forceinline__ float b2f_lo(unsigned int u) {
    return __uint_as_float(u << 16);
}
static __device__ __forceinline__ float b2f_hi(unsigned int u) {
    return __uint_as_float(u & 0xffff0000u);
}

static __device__ __forceinline__ void gl_lds16(const void* g, void* l) {
    __builtin_amdgcn_global_load_lds(
        (const __attribute__((address_space(1))) unsigned int*)g,
        (__attribute__((address_space(3))) unsigned int*)l, 16, 0, 0);
}

// ---------- K1: prep (xb | Wcol) + coarse presorted bucket chunks + zrow ----------
__global__ __launch_bounds__(256) void prep_coarse_kernel(
        const float* __restrict__ x,
        const float* __restrict__ W_rel,
        const float* __restrict__ W_self,
        const int* __restrict__ ei, const int* __restrict__ et,
        unsigned short* __restrict__ xb,
        unsigned short* __restrict__ Wcol,
        int* __restrict__ data,        // [nco][2048] block-major presorted records
        int* __restrict__ cmat,        // [nco][CROW] per-block bucket prefix rows
        unsigned short* __restrict__ zrow,   // sentinel row (KTOT elems) -> zero
        int Nn, int E, int xb_blocks, int wc_blocks, int co_blocks) {
    __shared__ int cnt[CROW];
    __shared__ int ps[256];
    __shared__ int recs[2048];
    const int t = threadIdx.x;

    if (blockIdx.x < (unsigned)xb_blocks) {
        int tt = blockIdx.x * 256 + t;
        int n = tt >> 5;             // 32 threads/row, 4 cols each
        int c = (tt & 31) * 4;
        if (n >= Nn) return;
        float4 v = *(const float4*)(x + (size_t)n * D + c);
        unsigned int p0 = f2b(v.x) | (f2b(v.y) << 16);
        unsigned int p1 = f2b(v.z) | (f2b(v.w) << 16);
        *(uint2*)(xb + (size_t)n * D + c) = make_uint2(p0, p1);
    } else if (blockIdx.x < (unsigned)(xb_blocks + wc_blocks)) {
        int idx = (blockIdx.x - xb_blocks) * 256 + t;
        if (idx >= KTOT * D) return;
        int c = idx >> 7;            // output col 0..1151
        int k = idx & 127;           // input dim
        float v = (c < KREL)
            ? W_rel[(size_t)((c >> 7) * D + k) * D + (c & 127)]   // W_rel[r][k][o]
            : W_self[(size_t)(c - KREL) * D + k];                 // W_self[o][k]
        Wcol[idx] = (unsigned short)f2b(v);
    } else if (blockIdx.x < (unsigned)(xb_blocks + wc_blocks + co_blocks)) {
        // ---- coarse: count -> LDS scan -> LDS scatter -> contiguous write ----
        int blk = blockIdx.x - xb_blocks - wc_blocks;
        for (int i = t; i < CROW; i += 256) cnt[i] = 0;
        __syncthreads();

        int rec[8], rb[8], rk[8];
        int e0 = blk * 2048;
#pragma unroll
        for (int j = 0; j < 8; ++j) {
            int e = e0 + j * 256 + t;
            bool ok = e < E;
            int s = ok ? ei[e] : 0;
            int d = ok ? ei[E + e] : 0;
            int r = ok ? et[e] : 0;
            rec[j] = (s * KTOT + r * D) | ((d & (BRANGE - 1)) << 26);
            rb[j] = ok ? (d >> BSHIFT) : -1;
            rk[j] = ok ? atomicAdd(&cnt[d >> BSHIFT], 1) : 0;
        }
        __syncthreads();

        // exclusive scan of cnt[784]: 4 entries/thread + Hillis-Steele on partials
        int s4 = 0;
#pragma unroll
        for (int i = 0; i < 4; ++i) {
            int idx = t * 4 + i;
            if (idx < CROW) s4 += cnt[idx];
        }
        ps[t] = s4;
        __syncthreads();
        for (int off = 1; off < 256; off <<= 1) {
            int v = (t >= off) ? ps[t - off] : 0;
            __syncthreads();
            ps[t] += v;
            __syncthreads();
        }
        int ex = t ? ps[t - 1] : 0;
#pragma unroll
        for (int i = 0; i < 4; ++i) {
            int idx = t * 4 + i;
            if (idx < CROW) {
                int c = cnt[idx];
                cnt[idx] = ex;
                cmat[(size_t)blk * CROW + idx] = ex;   // coalesced prefix row
                ex += c;
            }
        }
        __syncthreads();

        // scatter records into bucket order in LDS
#pragma unroll
        for (int j = 0; j < 8; ++j)
            if (rb[j] >= 0) recs[cnt[rb[j]] + rk[j]] = rec[j];
        __syncthreads();

        // contiguous full-line write: 8 KB per block
        int4* dsrc = (int4*)recs;
        int4* ddst = (int4*)(data + (size_t)blk * 2048);
        ddst[t * 2]     = dsrc[t * 2];
        ddst[t * 2 + 1] = dsrc[t * 2 + 1];
    } else {
        // zero the sentinel Z-row
        for (int i = t; i < KTOT / 4; i += 256)
            ((uint2*)zrow)[i] = make_uint2(0u, 0u);
    }
}

// ---------- K2: zgemm (XCD-contiguous) + fine (run-based) ----------
__global__ __launch_bounds__(256) void zgemm_fine_kernel(
        const unsigned short* __restrict__ xb,    // [npad][128]
        const unsigned short* __restrict__ Wcol,  // [1152][128]
        unsigned short* __restrict__ Z,           // [npad][1152]
        const int* __restrict__ data,             // [nco][2048] presorted chunks
        const int* __restrict__ cmat,             // [nco][CROW]
        int* __restrict__ sorted,                 // [nbkt][BCAP] output records
        int* __restrict__ offsets, int* __restrict__ deg,
        int Nn, int nstrip, int spx, int zg, int nco, int zoff) {
    __shared__ __align__(16) char smem[25600];    // union: zgemm 25600 | fine ~4KB

    if ((int)blockIdx.x < zg) {
        // ======== zgemm: 64 nodes x 64 cols; XCD-contiguous strip mapping ========
        unsigned short* Ws = (unsigned short*)smem;            // 16384 B
        unsigned short* Zs = (unsigned short*)(smem + 16384);  //  9216 B

        const int xcd = blockIdx.x & 7;
        const int i0  = blockIdx.x >> 3;
        const int strip = xcd * spx + i0 / 18;
        const int chunk = i0 % 18;
        if (strip >= nstrip) return;               // pad strips (uniform)

        const int tid  = threadIdx.x;
        const int lane = tid & 63;
        const int w    = tid >> 6;       // 0..3
        const int l16  = lane & 15;
        const int q    = lane >> 4;      // 0..3
        const int c0   = chunk * ZCH;
        const int n0   = strip * ZNB;
        const int n    = n0 + w * 16 + l16;    // this lane's node

        // xb B-frags: K=128 = 4 windows of 32, loaded ONCE
        short8 xq[4];
#pragma unroll
        for (int kw = 0; kw < 4; ++kw)
            xq[kw] = *(const short8*)(xb + (size_t)n * D + kw * 32 + q * 8);

        // stage W chunk: 1024 16B pieces; LDS slot s holds piece (s&15)^(c&15)
#pragma unroll
        for (int i = 0; i < 4; ++i) {
            int s = i * 256 + w * 64 + lane;
            int c = s >> 4;
            int p = (s & 15) ^ (c & 15);
            gl_lds16(Wcol + (size_t)(c0 + c) * D + p * 8,
                     &Ws[(size_t)(i * 256 + w * 64) * 8]);
        }
        __syncthreads();     // drains vmcnt (xq + stage)

        float4v acc[4] = {};
#pragma unroll
        for (int cg = 0; cg < 4; ++cg) {
#pragma unroll
            for (int kw = 0; kw < 4; ++kw) {
                // A-frag: row c = cg*16+l16 (c&15 == l16), logical piece kw*4+q
                short8 a = *(const short8*)(
                    &Ws[(((cg * 16 + l16) << 4) + ((kw * 4 + q) ^ l16)) * 8]);
                acc[cg] = __builtin_amdgcn_mfma_f32_16x16x32_bf16(
                    a, xq[kw], acc[cg], 0, 0, 0);
            }
        }

        // park accs in LDS (node row = w*16+l16, col = cg*16 + q*4)
#pragma unroll
        for (int cg = 0; cg < 4; ++cg) {
            unsigned int lo = f2b(acc[cg][0]) | (f2b(acc[cg][1]) << 16);
            unsigned int hi = f2b(acc[cg][2]) | (f2b(acc[cg][3]) << 16);
            *(uint2*)(&Zs[(w * 16 + l16) * ZSP + cg * 16 + q * 4]) = make_uint2(lo, hi);
        }
        __syncthreads();

        // full-line stores: thread t -> node row t>>2, 16B piece t&3 (+64B 2nd half)
        {
            int row = tid >> 2;
            int pc  = (tid & 3) * 8;     // elem offset 0,8,16,24
            short8 z0 = *(const short8*)(&Zs[row * ZSP + pc]);
            short8 z1 = *(const short8*)(&Zs[row * ZSP + pc + 32]);
            unsigned short* dst = Z + (size_t)(n0 + row) * KTOT + c0;
            *(short8*)(dst + pc)      = z0;
            *(short8*)(dst + pc + 32) = z1;
        }
    } else {
        // ======== fine: run-based gather from presorted chunks ========
        int* rs   = (int*)smem;               // 392 ints: run start (abs idx)
        int* re   = (int*)(smem + 1568);      // 392 ints: run end
        int* hist = (int*)(smem + 3136);      // 64: per-node count -> unused after
        int* curp = (int*)(smem + 3392);      // 64: per-node write cursor
        int b = blockIdx.x - zg;
        int t = threadIdx.x;

        for (int i = t; i < BRANGE; i += 256) hist[i] = 0;
        // run bounds for this bucket across all coarse blocks
        for (int i = t; i < nco; i += 256) {
            int s = cmat[(size_t)i * CROW + b];
            int e = cmat[(size_t)i * CROW + b + 1];
            rs[i] = i * 2048 + s;
            re[i] = i * 2048 + e;
        }
        __syncthreads();

        // pass A: per-node histogram
        for (int i = t; i < nco; i += 256)
            for (int k = rs[i]; k < re[i]; ++k)
                atomicAdd(&hist[((unsigned)data[k]) >> 26], 1);
        __syncthreads();

        // scan wave: offsets/deg, x8 sentinel pads, node cursors
        if (t < BRANGE) {
            int dsum = hist[t];
            int pad = (dsum + 7) & ~7;
            int x = pad;                       // inclusive scan across 64 lanes
            for (int off = 1; off < 64; off <<= 1) {
                int y = __shfl_up(x, off);
                if (t >= off) x += y;
            }
            int nb = b * BCAP + (x - pad);     // node base (exclusive prefix)
            int n0 = b * BRANGE + t;
            if (n0 < Nn) { offsets[n0] = nb; deg[n0] = dsum; }
            for (int i = dsum; i < pad; ++i)
                sorted[nb + i] = zoff;         // sentinel -> zeroed Z row
            curp[t] = nb;
        }
        __syncthreads();

        // pass B: scatter records (element offsets) into dst-grouped stream
        for (int i = t; i < nco; i += 256)
            for (int k = rs[i]; k < re[i]; ++k) {
                int rc = data[k];
                int node = ((unsigned)rc) >> 26;
                int pos = atomicAdd(&curp[node], 1);
                sorted[pos] = rc & 0x03FFFFFF;
            }
    }
}

// ---------- K3 gather: 16-deep unconditional batches; records = Z elem offsets ----------
__global__ __launch_bounds__(256) void gather_kernel(
        const unsigned short* __restrict__ Z,     // [npad+1][1152] (last = zero row)
        const int* __restrict__ offsets,          // node base, multiple of 8
        const int* __restrict__ deg,              // real in-degree
        const int* __restrict__ sorted,           // Z element offsets, sentinel-padded
        const float* __restrict__ bias,
        float* __restrict__ out,
        int Nn) {
    int node = blockIdx.x * 4 + (threadIdx.x >> 6);
    if (node >= Nn) return;
    int lane = threadIdx.x & 63;
    int laneoff = lane * 2;   // bf16-element offset within a 128-wide row

    int b0 = __builtin_amdgcn_readfirstlane(offsets[node]);
    int dg = __builtin_amdgcn_readfirstlane(deg[node]);
    float inv = 1.0f / fmaxf((float)dg, 1.0f);
    int len = (dg + 7) & ~7;       // padded length (sentinels add 0.0)

    float racx = 0.0f, racy = 0.0f;
    int e = b0;

    // 16-deep batches: all adds unconditional (sentinels hit the zero row)
    for (; e + 16 <= b0 + len; e += 16) {
        int pv[16];
#pragma unroll
        for (int j = 0; j < 16; ++j)
            pv[j] = __builtin_amdgcn_readfirstlane(sorted[e + j]);   // SGPR
        unsigned int u[16];
#pragma unroll
        for (int j = 0; j < 16; ++j)
            u[j] = *(const unsigned int*)(Z + (size_t)pv[j] + laneoff);
#pragma unroll
        for (int j = 0; j < 16; ++j) {
            racx += b2f_lo(u[j]);
            racy += b2f_hi(u[j]);
        }
    }
    // at most one 8-tail (len is a multiple of 8)
    if (e < b0 + len) {
        int pv[8];
#pragma unroll
        for (int j = 0; j < 8; ++j)
            pv[j] = __builtin_amdgcn_readfirstlane(sorted[e + j]);
        unsigned int u[8];
#pragma unroll
        for (int j = 0; j < 8; ++j)
            u[j] = *(const unsigned int*)(Z + (size_t)pv[j] + laneoff);
#pragma unroll
        for (int j = 0; j < 8; ++j) {
            racx += b2f_lo(u[j]);
            racy += b2f_hi(u[j]);
        }
    }

    // epilogue: out = relu(Z_self + bias + racc/deg)
    unsigned int zs = *(const unsigned int*)(Z + (size_t)node * KTOT + KREL + laneoff);
    float bx = bias[laneoff];
    float by = bias[laneoff + 1];
    float o0 = fmaxf(b2f_lo(zs) + bx + racx * inv, 0.0f);
    float o1 = fmaxf(b2f_hi(zs) + by + racy * inv, 0.0f);
    *(float2*)(out + (size_t)node * D + laneoff) = make_float2(o0, o1);
}

extern "C" void kernel_launch(void* const* d_in, const int* in_sizes, int n_in,
                              void* d_out, int out_size, void* d_ws, size_t ws_size,
                              hipStream_t stream) {
    const float* x      = (const float*)d_in[0];
    const float* W_rel  = (const float*)d_in[1];
    const float* W_self = (const float*)d_in[2];
    const float* W_bias = (const float*)d_in[3];
    const int*   ei     = (const int*)d_in[4];
    const int*   et     = (const int*)d_in[5];

    const int Nn = in_sizes[0] / D;       // 50000
    const int E  = in_sizes[4] / 2;       // 800000
    const int npad = ((Nn + ZNB - 1) / ZNB) * ZNB;        // 50048
    const int nstrip = npad / ZNB;                        // 782
    const int spx  = (nstrip + 7) / 8;                    // 98 strips per XCD
    const int zg   = spx * 8 * 18;                        // 14112 zgemm blocks
    const int nbkt = (Nn + BRANGE - 1) >> BSHIFT;         // 782
    const int nco  = (E + 2047) / 2048;                   // 391 coarse blocks
    const int zoff = npad * KTOT;                         // sentinel Z row offset

    // ---- workspace layout (256B aligned chunks) ----
    char* p = (char*)d_ws;
    auto take = [&](size_t bytes) { char* q = p; p += (bytes + 255) & ~(size_t)255; return q; };
    unsigned short* Z    = (unsigned short*)take(((size_t)npad * KTOT + KTOT) * sizeof(unsigned short));
    unsigned short* xb   = (unsigned short*)take((size_t)npad * D * sizeof(unsigned short));
    unsigned short* Wcol = (unsigned short*)take((size_t)KTOT * D * sizeof(unsigned short));
    int* offsets = (int*)take((size_t)Nn * sizeof(int));
    int* deg     = (int*)take((size_t)Nn * sizeof(int));
    int* data    = (int*)take((size_t)nco * 2048 * sizeof(int));   // presorted chunks
    int* cmat    = (int*)take((size_t)nco * CROW * sizeof(int));   // prefix rows
    int* sorted  = (int*)take((size_t)nbkt * BCAP * sizeof(int));  // dst-grouped stream
    unsigned short* zrow = Z + (size_t)npad * KTOT;

    const int xb_blocks = (Nn * 32 + 255) / 256;
    const int wc_blocks = (KTOT * D + 255) / 256;

    prep_coarse_kernel<<<xb_blocks + wc_blocks + nco + 1, 256, 0, stream>>>(
        x, W_rel, W_self, ei, et, xb, Wcol, data, cmat, zrow,
        Nn, E, xb_blocks, wc_blocks, nco);
    zgemm_fine_kernel<<<zg + nbkt, 256, 0, stream>>>(
        xb, Wcol, Z, data, cmat, sorted, offsets, deg,
        Nn, nstrip, spx, zg, nco, zoff);
    gather_kernel<<<(Nn + 3) / 4, 256, 0, stream>>>(Z, offsets, deg, sorted, W_bias,
                                                    (float*)d_out, Nn);
}